// Round 7
// baseline (1134.544 us; speedup 1.0000x reference)
//
#include <hip/hip_runtime.h>

// ---------------------------------------------------------------------------
// GatedDeltaProduct: B=2,T=1024,HID=2048, NH=2, H=6, DK=256, DV=512, CHUNK=64
// Inputs fp32, output fp32. Internal bf16 MFMA. WY chunked gated delta rule.
// R9: precompute_chunk C3 register-resident substitution (394us -> gone).
// R11: scan counted vmcnt + merged phase + b64 LDS + TBV[v][t] + XCD swizzle.
//      Measured: FETCH 178->47MB (swizzle works) but dur 166->163 (neutral) —
//      kernel is LATENCY-bound at 1-wave occupancy; counted vmcnt can't help
//      when loads are issued and waited within the same chunk.
// R15: scan 2-wave cooperative blocks (128 thr) + register-resident NTW/Qg:
//   * wave w owns uac tiles {2w,2w+1}, oac tile w, S-phase g2 {2w,2w+1}
//   * NTW/Qg loaded per-wave into VGPR frags (each wave reads only its rows)
//     -> no LDS staging, no stage barrier, phase1 ds_reads 56->8/chunk
//   * LDS 59.9KB -> ~10.7KB (S+U only); occupancy ~1.5 -> ~4-8 waves/CU
//   * 2 raw s_barriers/chunk (U before M@u; S across chunks) w/ lgkmcnt(0)
//   * counted vmcnt(20/16/0) per wave (safe incl. in-flight O stores)
// ---------------------------------------------------------------------------

typedef short bf16x8 __attribute__((ext_vector_type(8)));
typedef short bf16x4 __attribute__((ext_vector_type(4)));
typedef float f32x4 __attribute__((ext_vector_type(4)));

__device__ __forceinline__ float bf2f(short s) {
  unsigned u = ((unsigned)(unsigned short)s) << 16;
  float f; __builtin_memcpy(&f, &u, 4); return f;
}
__device__ __forceinline__ short f2bf(float f) {
  unsigned u; __builtin_memcpy(&u, &f, 4);
  u = (u + 0x7FFFu + ((u >> 16) & 1u)) >> 16;
  return (short)u;
}
__device__ __forceinline__ f32x4 MFMA(bf16x8 a, bf16x8 b, f32x4 c) {
  return __builtin_amdgcn_mfma_f32_16x16x32_bf16(a, b, c, 0, 0, 0);
}
// async global->LDS, 16B per lane; lds dest = wave-uniform base + lane*16
__device__ __forceinline__ void gl_lds16(const short* g, short* l) {
  __builtin_amdgcn_global_load_lds(
      (const __attribute__((address_space(1))) unsigned int*)g,
      (__attribute__((address_space(3))) unsigned int*)l, 16, 0, 0);
}

#define PJ_N 13824   // [q 0:1536][k0][k1][v0 4608:][v1 7680:][gate 10752:]
#define NTOK 2048    // B*T rows

// ---------------------------------------------------------------------------
// fp32 -> bf16 bulk convert (for x). n multiple of 8.
__global__ __launch_bounds__(256) void cvt_bf16(
    const float* __restrict__ src, short* __restrict__ dst, int n)
{
  int i = (blockIdx.x * 256 + threadIdx.x) * 8;
  if (i + 8 <= n) {
    float4 a = *(const float4*)(src + i);
    float4 b = *(const float4*)(src + i + 4);
    short v[8] = {f2bf(a.x), f2bf(a.y), f2bf(a.z), f2bf(a.w),
                  f2bf(b.x), f2bf(b.y), f2bf(b.z), f2bf(b.w)};
    uint4 u; __builtin_memcpy(&u, v, 16);
    *(uint4*)(dst + i) = u;
  }
}

// ---------------------------------------------------------------------------
// Weight transpose + convert: W (K x N, fp32) -> WT (N x K, bf16).
__global__ __launch_bounds__(256) void transpose_w(
    const float* __restrict__ W, short* __restrict__ WT, int K, int N)
{
  int lane = threadIdx.x & 63, y = threadIdx.x >> 6;
  int n = blockIdx.x * 64 + lane;
  for (int k0 = y * 8; k0 < K; k0 += 32) {
    short v[8];
    #pragma unroll
    for (int j = 0; j < 8; ++j) v[j] = f2bf(W[(size_t)(k0 + j) * N + n]);
    uint4 u; __builtin_memcpy(&u, v, 16);
    *(uint4*)(WT + (size_t)n * K + k0) = u;
  }
}

// ---------------------------------------------------------------------------
// GEMM: C[M,N] = A[M,K] @ B, given BT (N x K). bf16 in, fp32 accum.
// 1-D grid, XCD-aware. global_load_lds staging, XOR-swizzled LDS.
template<bool F32OUT>
__global__ __launch_bounds__(256) void gemm_bt(
    const short* __restrict__ A, const short* __restrict__ BT,
    void* __restrict__ Cp, int M, int N, int K)
{
  __shared__ short As[128 * 64];
  __shared__ short Bs[128 * 64];
  const int tid = threadIdx.x;
  const int lane = tid & 63, wv = tid >> 6;
  const int quad = lane >> 4, l16 = lane & 15;
  const int j = blockIdx.x;
  const int xcd = j & 7, local = j >> 3;
  const int mtile = local & 15, ng = local >> 4;
  const int ntile = ng * 8 + xcd;
  if (ntile * 128 >= N) return;     // pad blocks no-op (uniform per block)
  const int m0 = mtile * 128, n0 = ntile * 128;
  const int wm = (wv >> 1) * 64, wn = (wv & 1) * 64;
  const int lrow = lane >> 3;              // 0..7 within staging call
  const int lperm = (lane & 7) ^ lrow;     // xor swizzle source segment
  const int xr = l16 & 7;                  // read-side xor key
  f32x4 zz = {0.f, 0.f, 0.f, 0.f};
  f32x4 acc[4][4];
  #pragma unroll
  for (int i = 0; i < 4; ++i)
    #pragma unroll
    for (int jj = 0; jj < 4; ++jj) acc[i][jj] = zz;

  for (int k0 = 0; k0 < K; k0 += 64) {
    __syncthreads();
    #pragma unroll
    for (int c = 0; c < 4; ++c) {
      int row = (wv * 4 + c) * 8 + lrow;
      gl_lds16(A  + (size_t)(m0 + row) * K + k0 + lperm * 8,
               As + (wv * 4 + c) * 512);
      gl_lds16(BT + (size_t)(n0 + row) * K + k0 + lperm * 8,
               Bs + (wv * 4 + c) * 512);
    }
    __syncthreads();
    #pragma unroll
    for (int kk = 0; kk < 64; kk += 32) {
      const int ksb = kk >> 3;
      bf16x8 af[4], bfr[4];
      #pragma unroll
      for (int i = 0; i < 4; ++i)
        af[i] = *(const bf16x8*)(As + (wm + i * 16 + l16) * 64 +
                                 (((ksb + quad) ^ xr) << 3));
      #pragma unroll
      for (int jj = 0; jj < 4; ++jj)
        bfr[jj] = *(const bf16x8*)(Bs + (wn + jj * 16 + l16) * 64 +
                                   (((ksb + quad) ^ xr) << 3));
      #pragma unroll
      for (int i = 0; i < 4; ++i)
        #pragma unroll
        for (int jj = 0; jj < 4; ++jj)
          acc[i][jj] = MFMA(af[i], bfr[jj], acc[i][jj]);
    }
  }
  #pragma unroll
  for (int i = 0; i < 4; ++i)
    #pragma unroll
    for (int jj = 0; jj < 4; ++jj)
      #pragma unroll
      for (int r = 0; r < 4; ++r) {
        int row = m0 + wm + i * 16 + quad * 4 + r;
        int col = n0 + wn + jj * 16 + l16;
        if (F32OUT) ((float*)Cp)[(size_t)row * N + col] = acc[i][jj][r];
        else        ((short*)Cp)[(size_t)row * N + col] = f2bf(acc[i][jj][r]);
      }
}

// ---------------------------------------------------------------------------
// beta (sigmoid(x@b_ws[i])) and g (-exp(A_log)*softplus(x@a_w+dt_bias)).
__global__ __launch_bounds__(64) void proj_small(
    const float* __restrict__ x, const float* __restrict__ b_ws,
    const float* __restrict__ a_w, const float* __restrict__ A_log,
    const float* __restrict__ dt_bias,
    float* __restrict__ Beta0, float* __restrict__ Beta1, float* __restrict__ G)
{
  int row = blockIdx.x, lane = threadIdx.x;
  float p[18];
  #pragma unroll
  for (int j = 0; j < 18; ++j) p[j] = 0.f;
  for (int k = lane; k < 2048; k += 64) {
    float xv = x[(size_t)row * 2048 + k];
    const float* b0 = b_ws + (size_t)k * 6;
    const float* b1 = b_ws + (size_t)2048 * 6 + (size_t)k * 6;
    const float* aw = a_w + (size_t)k * 6;
    #pragma unroll
    for (int j = 0; j < 6; ++j) {
      p[j]      += xv * b0[j];
      p[6 + j]  += xv * b1[j];
      p[12 + j] += xv * aw[j];
    }
  }
  #pragma unroll
  for (int j = 0; j < 18; ++j) {
    #pragma unroll
    for (int off = 32; off > 0; off >>= 1)
      p[j] += __shfl_down(p[j], off);
  }
  if (lane == 0) {
    #pragma unroll
    for (int j = 0; j < 6; ++j) {
      Beta0[(size_t)row * 6 + j] = 1.f / (1.f + expf(-p[j]));
      Beta1[(size_t)row * 6 + j] = 1.f / (1.f + expf(-p[6 + j]));
      float z = p[12 + j] + dt_bias[j];
      float sp = (z > 15.f) ? z : log1pf(expf(z));
      G[(size_t)row * 6 + j] = -expf(A_log[j]) * sp;
    }
  }
}

// ---------------------------------------------------------------------------
// Conv(K=4 causal, depthwise) + SiLU + per-head l2norm (q/k). grid (2048, 6).
__global__ __launch_bounds__(256) void conv_norm_qk(
    const short* __restrict__ P, const float* __restrict__ convw,
    short* __restrict__ dst, int colofs, float scale)
{
  __shared__ float red[256];
  int c = threadIdx.x, h = blockIdx.y, row = blockIdx.x;
  int t = row & 1023;
  int ch = colofs + h * 256 + c;
  const float* cw = convw + (size_t)(h * 256 + c) * 4;
  float acc = 0.f;
  #pragma unroll
  for (int j = 0; j < 4; ++j) {
    int tt = t - 3 + j;
    if (tt >= 0) acc += bf2f(P[(size_t)(row - 3 + j) * PJ_N + ch]) * cw[j];
  }
  float y = acc / (1.f + expf(-acc));   // silu
  red[c] = y * y;
  __syncthreads();
  for (int s = 128; s > 0; s >>= 1) {
    if (c < s) red[c] += red[c + s];
    __syncthreads();
  }
  float nrm = rsqrtf(red[0] + 1e-12f) * scale;
  dst[((size_t)row * 6 + h) * 256 + c] = f2bf(y * nrm);
}

// Conv + SiLU for v. grid (2048, 12).
__global__ __launch_bounds__(256) void conv_v(
    const short* __restrict__ P, const float* __restrict__ convw,
    short* __restrict__ dst, int colofs)
{
  int cg = blockIdx.y * 256 + threadIdx.x;
  int row = blockIdx.x;
  int t = row & 1023;
  const float* cw = convw + (size_t)cg * 4;
  float acc = 0.f;
  #pragma unroll
  for (int j = 0; j < 4; ++j) {
    int tt = t - 3 + j;
    if (tt >= 0) acc += bf2f(P[(size_t)(row - 3 + j) * PJ_N + colofs + cg]) * cw[j];
  }
  float y = acc / (1.f + expf(-acc));
  dst[(size_t)row * 3072 + cg] = f2bf(y);
}

// ---------------------------------------------------------------------------
// Per-(b,h,chunk) precompute of WY operands. grid (32, 6, 2), block 256.
// Qg/Mm store only odd interleaved rows (32 per chunk).
// TBV stored TRANSPOSED: [v_full=512][t=64] (R11, for b64 loads in scan).
#define KBLD 264
#define R2LD 72
#define WTLD 72
__global__ __launch_bounds__(256) void precompute_chunk(
    const short* __restrict__ Qc, const short* __restrict__ K0c, const short* __restrict__ K1c,
    const short* __restrict__ V0c, const short* __restrict__ V1c,
    const float* __restrict__ Beta0, const float* __restrict__ Beta1, const float* __restrict__ G,
    short* __restrict__ NTW, short* __restrict__ Qg, short* __restrict__ KdT,
    short* __restrict__ Mm, short* __restrict__ TBV, float* __restrict__ dC)
{
  __shared__ short r0[256 * 72];   // kb (64 x KBLD) -> wt (256 x WTLD) -> BVT
  __shared__ float Xs[64 * 64];    // A matrix (f32), consumed by substitution
  __shared__ short r2[64 * 72];    // KK^T (bf16) -> X (bf16)
  const int tid = threadIdx.x;
  const int lane = tid & 63, wv = tid >> 6;
  const int quad = lane >> 4, l16 = lane & 15;
  const int c = blockIdx.x, h = blockIdx.y, b = blockIdx.z;
  const int i0 = c * 32;
  const size_t idx = (size_t)((b * 6 + h) * 32 + c);
  short* kb = r0;
  f32x4 zz = {0.f, 0.f, 0.f, 0.f};
  bf16x8 z8 = {0, 0, 0, 0, 0, 0, 0, 0};

  // per-lane g/beta for interleaved position t = lane; wave-prefix cumsum
  float gv, betaL;
  {
    int t = lane, par = t & 1, i = i0 + (t >> 1);
    size_t gofs = (size_t)(b * 1024 + i) * 6 + h;
    gv = par ? 0.f : G[gofs];
    betaL = par ? Beta1[gofs] : Beta0[gofs];
  }
  float cum = gv;
  #pragma unroll
  for (int off = 1; off < 64; off <<= 1) {
    float nb = __shfl_up(cum, off);
    if (lane >= off) cum += nb;
  }
  float c63 = __shfl(cum, 63);
  float eBt = expf(cum);          // exp(B_t)
  float eRem = expf(c63 - cum);   // exp(B63 - B_t)
  float wsc = betaL * eBt;        // beta_t exp(B_t)
  if (tid == 0) dC[idx] = expf(c63);

  // stage k chunk (interleaved parities) into kb
  {
    int row = tid >> 2, seg = (tid & 3) * 64;
    int par = row & 1, i = i0 + (row >> 1);
    const short* src = (par ? K1c : K0c) + ((size_t)(b * 1024 + i) * 6 + h) * 256 + seg;
    short* dp = kb + row * KBLD + seg;
    #pragma unroll
    for (int e = 0; e < 64; e += 8)
      *(uint4*)(dp + e) = *(const uint4*)(src + e);
  }
  __syncthreads();

  // KK^T (bf16 into r2). wave = t row-tile.
  {
    f32x4 acc[4];
    #pragma unroll
    for (int ts = 0; ts < 4; ++ts) acc[ts] = zz;
    #pragma unroll
    for (int ks = 0; ks < 8; ++ks) {
      bf16x8 af = *(const bf16x8*)(kb + (wv * 16 + l16) * KBLD + ks * 32 + quad * 8);
      #pragma unroll
      for (int ts = 0; ts < 4; ++ts) {
        bf16x8 bfv = *(const bf16x8*)(kb + (ts * 16 + l16) * KBLD + ks * 32 + quad * 8);
        acc[ts] = MFMA(af, bfv, acc[ts]);
      }
    }
    #pragma unroll
    for (int ts = 0; ts < 4; ++ts)
      #pragma unroll
      for (int r = 0; r < 4; ++r)
        r2[(wv * 16 + quad * 4 + r) * R2LD + ts * 16 + l16] = f2bf(acc[ts][r]);
  }
  // QK^T -> M (masked, decayed; odd rows only) directly to global
  {
    f32x4 acc[4];
    #pragma unroll
    for (int ts = 0; ts < 4; ++ts) acc[ts] = zz;
    int t_row = wv * 16 + l16;
    int podd = t_row & 1, iq = i0 + (t_row >> 1);
    const short* qrow = Qc + ((size_t)(b * 1024 + iq) * 6 + h) * 256;
    #pragma unroll
    for (int ks = 0; ks < 8; ++ks) {
      bf16x8 af = z8;
      if (podd) af = *(const bf16x8*)(qrow + ks * 32 + quad * 8);
      #pragma unroll
      for (int ts = 0; ts < 4; ++ts) {
        bf16x8 bfv = *(const bf16x8*)(kb + (ts * 16 + l16) * KBLD + ks * 32 + quad * 8);
        acc[ts] = MFMA(af, bfv, acc[ts]);
      }
    }
    short* Mp = Mm + idx * 2048;
    #pragma unroll
    for (int ts = 0; ts < 4; ++ts)
      #pragma unroll
      for (int r = 1; r < 4; r += 2) {       // odd rows only
        int t = wv * 16 + quad * 4 + r, s = ts * 16 + l16;
        float ct = __shfl(cum, t), cs = __shfl(cum, s);
        float v = (s <= t) ? acc[ts][r] * expf(ct - cs) : 0.f;
        Mp[(t >> 1) * 64 + s] = f2bf(v);
      }
  }
  // Qg (odd rows only): Qg[th][d] = exp(B_{2th+1}) q_{2th+1}[d]
  {
    int th = tid >> 3, dseg = (tid & 7) * 32;
    int t = th * 2 + 1;
    float sc = __shfl(eBt, t);
    const short* qrow = Qc + ((size_t)(b * 1024 + i0 + th) * 6 + h) * 256 + dseg;
    short* qgp = Qg + idx * 8192 + (size_t)th * 256 + dseg;
    #pragma unroll
    for (int e = 0; e < 32; e += 8) {
      bf16x8 v = *(const bf16x8*)(qrow + e);
      bf16x8 w;
      #pragma unroll
      for (int q2 = 0; q2 < 8; ++q2) w[q2] = f2bf(bf2f(v[q2]) * sc);
      *(bf16x8*)(qgp + e) = w;
    }
  }
  // KdT[d][t] = exp(B63-B_t) k_t[d]
  {
    int d = tid;
    short buf[64];
    #pragma unroll
    for (int t = 0; t < 64; ++t) {
      float sc = __shfl(eRem, t);
      buf[t] = f2bf(bf2f(kb[t * KBLD + d]) * sc);
    }
    short* kp = KdT + idx * 16384 + (size_t)d * 64;
    #pragma unroll
    for (int e = 0; e < 64; e += 8) {
      uint4 v; __builtin_memcpy(&v, buf + e, 16);
      *(uint4*)(kp + e) = v;
    }
  }
  __syncthreads();

  // C1: cache kb column d = tid in registers
  short colv[64];
  {
    int d = tid;
    #pragma unroll
    for (int t = 0; t < 64; ++t) colv[t] = kb[t * KBLD + d];
  }
  // A precompute (parallel, all 256 threads): Xs[t][s] = beta_t exp(ct-cs)
  // KKT[t][s] for s<t else 0. Per iteration t is wave-uniform; s == lane, so
  // cs needs no shuffle at all.
  #pragma unroll
  for (int k = 0; k < 16; ++k) {
    int t = wv + k * 4;
    float bt = __shfl(betaL, t);
    float ct = __shfl(cum, t);
    float a = (lane < t) ? bt * expf(ct - cum) * bf2f(r2[t * R2LD + lane]) : 0.f;
    Xs[t * 64 + lane] = a;
  }
  __syncthreads();
  // C2: wt[d][s] = beta_s exp(B_s) k_s[d] (over r0)
  {
    int d = tid;
    short wrow[64];
    #pragma unroll
    for (int s = 0; s < 64; ++s) wrow[s] = f2bf(bf2f(colv[s]) * __shfl(wsc, s));
    short* wp = r0 + d * WTLD;
    #pragma unroll
    for (int e = 0; e < 64; e += 8) {
      uint4 v; __builtin_memcpy(&v, wrow + e, 16);
      *(uint4*)(wp + e) = v;
    }
  }
  // C3: wave0 solves X = (I+A)^-1 by forward substitution, column j = lane,
  // X entirely in registers (static triangular unroll; A read as broadcast
  // float2 from LDS). Writes bf16 X directly into r2.
  if (wv == 0) {
    const int j = lane;
    float xcol[64];
    #pragma unroll
    for (int t = 0; t < 64; ++t) {
      float sa0 = 0.f, sa1 = 0.f;
      const float2* ap = (const float2*)(Xs + t * 64);
      #pragma unroll
      for (int s = 0; s + 1 < t; s += 2) {
        float2 av = ap[s >> 1];
        sa0 += av.x * xcol[s];
        sa1 += av.y * xcol[s + 1];
      }
      if (t & 1) sa0 += Xs[t * 64 + (t - 1)] * xcol[t - 1];
      float xv = ((t == j) ? 1.f : 0.f) - (sa0 + sa1);
      xcol[t] = xv;
      r2[t * R2LD + j] = f2bf(xv);
    }
  }
  __syncthreads();
  // NTW = -(X @ W)
  {
    f32x4 acc[4][4];
    #pragma unroll
    for (int i = 0; i < 4; ++i)
      #pragma unroll
      for (int j = 0; j < 4; ++j) acc[i][j] = zz;
    #pragma unroll
    for (int ks = 0; ks < 2; ++ks) {
      bf16x8 af[4], bfv[4];
      #pragma unroll
      for (int tt = 0; tt < 4; ++tt)
        af[tt] = *(const bf16x8*)(r2 + (tt * 16 + l16) * R2LD + ks * 32 + quad * 8);
      #pragma unroll
      for (int dt = 0; dt < 4; ++dt)
        bfv[dt] = *(const bf16x8*)(r0 + ((wv * 4 + dt) * 16 + l16) * WTLD + ks * 32 + quad * 8);
      #pragma unroll
      for (int tt = 0; tt < 4; ++tt)
        #pragma unroll
        for (int dt = 0; dt < 4; ++dt)
          acc[tt][dt] = MFMA(af[tt], bfv[dt], acc[tt][dt]);
    }
    short* np = NTW + idx * 16384;
    #pragma unroll
    for (int tt = 0; tt < 4; ++tt)
      #pragma unroll
      for (int dt = 0; dt < 4; ++dt)
        #pragma unroll
        for (int r = 0; r < 4; ++r) {
          int t = tt * 16 + quad * 4 + r, d = (wv * 4 + dt) * 16 + l16;
          np[t * 256 + d] = f2bf(-acc[tt][dt][r]);
        }
  }
  __syncthreads();
  // TBV = X @ (beta*v), two DV halves through r0; stored [v_full][t] (b64)
  for (int vh = 0; vh < 2; ++vh) {
    {
      int vl = tid;
      short bv[64];
      #pragma unroll
      for (int t = 0; t < 64; ++t) {
        int par = t & 1, i = i0 + (t >> 1);
        const short* src = (par ? V1c : V0c) + (size_t)(b * 1024 + i) * 3072 + h * 512 + vh * 256 + vl;
        bv[t] = f2bf(bf2f(*src) * __shfl(betaL, t));
      }
      short* bp = r0 + vl * WTLD;
      #pragma unroll
      for (int e = 0; e < 64; e += 8) {
        uint4 v; __builtin_memcpy(&v, bv + e, 16);
        *(uint4*)(bp + e) = v;
      }
    }
    __syncthreads();
    {
      f32x4 acc[4][4];
      #pragma unroll
      for (int i = 0; i < 4; ++i)
        #pragma unroll
        for (int j = 0; j < 4; ++j) acc[i][j] = zz;
      #pragma unroll
      for (int ks = 0; ks < 2; ++ks) {
        bf16x8 af[4], bfv[4];
        #pragma unroll
        for (int tt = 0; tt < 4; ++tt)
          af[tt] = *(const bf16x8*)(r2 + (tt * 16 + l16) * R2LD + ks * 32 + quad * 8);
        #pragma unroll
        for (int vt = 0; vt < 4; ++vt)
          bfv[vt] = *(const bf16x8*)(r0 + ((wv * 4 + vt) * 16 + l16) * WTLD + ks * 32 + quad * 8);
        #pragma unroll
        for (int tt = 0; tt < 4; ++tt)
          #pragma unroll
          for (int vt = 0; vt < 4; ++vt)
            acc[tt][vt] = MFMA(af[tt], bfv[vt], acc[tt][vt]);
      }
      short* tp = TBV + idx * 32768;
      #pragma unroll
      for (int tt = 0; tt < 4; ++tt)
        #pragma unroll
        for (int vt = 0; vt < 4; ++vt) {
          // D frag: row = t = tt*16+quad*4+r, col = v = (wv*4+vt)*16+l16
          int vfull = vh * 256 + (wv * 4 + vt) * 16 + l16;
          int t0 = tt * 16 + quad * 4;
          short w[4];
          #pragma unroll
          for (int r = 0; r < 4; ++r) w[r] = f2bf(acc[tt][vt][r]);
          uint2 uv; __builtin_memcpy(&uv, w, 8);
          *(uint2*)(tp + (size_t)vfull * 64 + t0) = uv;
        }
    }
    __syncthreads();
  }
}

// ---------------------------------------------------------------------------
// Scan: 2-wave blocks (128 thr) per (b,h,16-col DV slice). grid 384.
// R15: NTW/Qg register-resident per wave (no LDS staging); wave w owns
// uac tiles {2w,2w+1}, oac tile w, S-phase g2 {2w,2w+1}. Two raw barriers
// per chunk (U before M@u; S across chunks). Counted vmcnt(20/16/0).
#define SLD 264
#define ULD 72
__global__ __launch_bounds__(128) void scan_kernel(
    const short* __restrict__ NTW, const short* __restrict__ Qg,
    const short* __restrict__ KdT, const short* __restrict__ Mm,
    const short* __restrict__ TBV, const float* __restrict__ dC,
    short* __restrict__ O)
{
  __shared__ short S[16 * SLD];     // state slice [v_local][d], bf16 (8.4KB)
  __shared__ short U[16 * ULD];     // u slice [v_local][t], bf16 (2.3KB)
  const int tid = threadIdx.x;
  const int lane = tid & 63, w = tid >> 6;
  const int quad = lane >> 4, l16 = lane & 15;
  // XCD-aware swizzle (bijective, 384 = 8 xcd * 48): the 32 slice-blocks of
  // one bh land on <=2 XCDs -> shared NTW/Qg/KdT/Mm hit the same L2.
  const int gid = (blockIdx.x & 7) * 48 + (blockIdx.x >> 3);
  const int bh = gid >> 5, slice = gid & 31;
  const int b = bh / 6, h = bh % 6;
  const int vbase = slice * 16;
  f32x4 zz = {0.f, 0.f, 0.f, 0.f};
  for (int e = tid; e < 16 * SLD; e += 128) S[e] = 0;
  __syncthreads();

  for (int c = 0; c < 32; ++c) {
    size_t idx = (size_t)(bh * 32 + c);
    const short* ntw = NTW + idx * 16384;
    const short* qg  = Qg  + idx * 8192;
    const short* kdt = KdT + idx * 16384;
    const short* mp  = Mm  + idx * 2048;
    const short* tb  = TBV + idx * 32768;

    // --- group A: NTW (16) + Qg (8) register fragments (24 vmem) ---
    bf16x8 ntwr[2][8], qgr[8];
    #pragma unroll
    for (int j = 0; j < 2; ++j)
      #pragma unroll
      for (int ks = 0; ks < 8; ++ks)
        ntwr[j][ks] = *(const bf16x8*)(
            ntw + (size_t)((2 * w + j) * 16 + l16) * 256 + ks * 32 + quad * 8);
    #pragma unroll
    for (int ks = 0; ks < 8; ++ks)
      qgr[ks] = *(const bf16x8*)(
          qg + (size_t)(w * 16 + l16) * 256 + ks * 32 + quad * 8);
    __builtin_amdgcn_sched_barrier(0);

    // --- group B: dc + Mm (2) + TBV (2)  (4-5 vmem) ---
    float dc = dC[idx];
    bf16x8 mmr2[2];
    #pragma unroll
    for (int ks = 0; ks < 2; ++ks)
      mmr2[ks] = *(const bf16x8*)(mp + (w * 16 + l16) * 64 + ks * 32 + quad * 8);
    bf16x4 tbv2[2];
    #pragma unroll
    for (int j = 0; j < 2; ++j)
      tbv2[j] = *(const bf16x4*)(
          tb + (size_t)(vbase + l16) * 64 + (2 * w + j) * 16 + quad * 4);
    __builtin_amdgcn_sched_barrier(0);

    // --- group C: KdT own g2 halves (16 b128) ---
    bf16x8 kdr2[2][2][4];
    #pragma unroll
    for (int j = 0; j < 2; ++j)
      #pragma unroll
      for (int ks = 0; ks < 2; ++ks)
        #pragma unroll
        for (int dt = 0; dt < 4; ++dt)
          kdr2[j][ks][dt] = *(const bf16x8*)(
              kdt + (size_t)(((2 * w + j) * 4 + dt) * 16 + l16) * 64 + ks * 32 + quad * 8);
    __builtin_amdgcn_sched_barrier(0);

    // group A (oldest 24) complete; B+C (>=20) may stay in flight
    asm volatile("s_waitcnt vmcnt(20)" ::: "memory");
    __builtin_amdgcn_sched_barrier(0);

    // --- phase 1: uac2 = NTW@S0 (2 tiles), oac = Qg@S0 (1 tile) ---
    f32x4 uac2[2], oac;
    uac2[0] = zz; uac2[1] = zz; oac = zz;
    __builtin_amdgcn_s_setprio(1);
    #pragma unroll
    for (int ks = 0; ks < 8; ++ks) {
      bf16x8 bfv = *(const bf16x8*)(S + l16 * SLD + ks * 32 + quad * 8);
      uac2[0] = MFMA(ntwr[0][ks], bfv, uac2[0]);
      uac2[1] = MFMA(ntwr[1][ks], bfv, uac2[1]);
      oac     = MFMA(qgr[ks],     bfv, oac);
    }
    __builtin_amdgcn_s_setprio(0);

    // group B (dc/mm/tbv) done; kdr (16) may stay in flight
    asm volatile("s_waitcnt vmcnt(16)" ::: "memory");
    __builtin_amdgcn_sched_barrier(0);

    // --- u = uac + TBV -> U (own tiles, b64 writes) ---
    #pragma unroll
    for (int j = 0; j < 2; ++j) {
      short wb[4];
      #pragma unroll
      for (int r = 0; r < 4; ++r) wb[r] = f2bf(uac2[j][r] + bf2f(tbv2[j][r]));
      uint2 uv; __builtin_memcpy(&uv, wb, 8);
      *(uint2*)(U + l16 * ULD + (2 * w + j) * 16 + quad * 4) = uv;
    }
    // drain own U writes (and phase1 S reads), then sync both waves:
    // after this barrier U is complete and no wave still reads old S.
    asm volatile("s_waitcnt lgkmcnt(0)" ::: "memory");
    __builtin_amdgcn_s_barrier();
    __builtin_amdgcn_sched_barrier(0);

    // --- o += M @ u (own tile) ---
    #pragma unroll
    for (int ks = 0; ks < 2; ++ks) {
      bf16x8 bfv = *(const bf16x8*)(U + l16 * ULD + ks * 32 + quad * 8);
      oac = MFMA(mmr2[ks], bfv, oac);
    }

    // all kdr loads done before S-phase (latency hidden under phase1+o)
    asm volatile("s_waitcnt vmcnt(0)" ::: "memory");
    __builtin_amdgcn_sched_barrier(0);

    // --- O store (own tile; overlaps S-phase MFMAs) ---
    #pragma unroll
    for (int r = 0; r < 4; ++r) {
      int th = w * 16 + quad * 4 + r;
      int i = c * 32 + th;
      O[((size_t)(b * 1024 + i) * 6 + h) * 512 + vbase + l16] = f2bf(oac[r]);
    }

    // --- S1 = dc * S0 + KdT @ u (own g2 halves, b64 S reads/writes) ---
    __builtin_amdgcn_s_setprio(1);
    #pragma unroll
    for (int j = 0; j < 2; ++j) {
      const int g2 = 2 * w + j;
      f32x4 sac[4];
      #pragma unroll
      for (int dt = 0; dt < 4; ++dt) {
        bf16x4 sv = *(const bf16x4*)(S + l16 * SLD + (g2 * 4 + dt) * 16 + quad * 4);
        #pragma unroll
        for (int r = 0; r < 4; ++r) sac[dt][r] = dc * bf2f(sv[r]);
      }
      #pragma unroll
      for (int ks = 0; ks < 2; ++ks) {
        bf16x8 bfv = *(const bf16x8*)(U + l16 * ULD + ks * 32 + quad * 8);
        #pragma unroll
        for (int dt = 0; dt < 4; ++dt)
          sac[dt] = MFMA(kdr2[j][ks][dt], bfv, sac[dt]);
      }
      #pragma unroll
      for (int dt = 0; dt < 4; ++dt) {
        short wb[4];
        #pragma unroll
        for (int r = 0; r < 4; ++r) wb[r] = f2bf(sac[dt][r]);
        uint2 uv; __builtin_memcpy(&uv, wb, 8);
        *(uint2*)(S + l16 * SLD + (g2 * 4 + dt) * 16 + quad * 4) = uv;
      }
    }
    __builtin_amdgcn_s_setprio(0);
    // drain S writes (and U reads), sync: next chunk's phase1 reads all of S
    asm volatile("s_waitcnt lgkmcnt(0)" ::: "memory");
    __builtin_amdgcn_s_barrier();
    __builtin_amdgcn_sched_barrier(0);
  }
}

// ---------------------------------------------------------------------------
// RMS-norm over DV per (b,t,h), times silu(gate). grid (2048, 6).
__global__ __launch_bounds__(256) void rms_gate(
    const short* __restrict__ O, const short* __restrict__ P,
    const float* __restrict__ onw, short* __restrict__ OutPre)
{
  __shared__ float red[256];
  int tid = threadIdx.x, h = blockIdx.y, row = blockIdx.x;
  size_t base = ((size_t)row * 6 + h) * 512;
  float a = bf2f(O[base + tid]), b2 = bf2f(O[base + 256 + tid]);
  red[tid] = a * a + b2 * b2;
  __syncthreads();
  for (int s = 128; s > 0; s >>= 1) {
    if (tid < s) red[tid] += red[tid + s];
    __syncthreads();
  }
  float r = rsqrtf(red[0] * (1.f / 512.f) + 1e-5f);
  #pragma unroll
  for (int half = 0; half < 2; ++half) {
    int col = tid + half * 256;
    float ov = half ? b2 : a;
    float g = bf2f(P[(size_t)row * PJ_N + 10752 + h * 512 + col]);
    float sg = g / (1.f + expf(-g));
    OutPre[(size_t)row * 3072 + h * 512 + col] = f2bf(ov * r * onw[col] * sg);
  }
}

// ---------------------------------------------------------------------------
extern "C" void kernel_launch(void* const* d_in, const int* in_sizes, int n_in,
                              void* d_out, int out_size, void* d_ws, size_t ws_size,
                              hipStream_t stream) {
  const float* x        = (const float*)d_in[0];
  const float* q_w      = (const float*)d_in[1];
  const float* k_ws     = (const float*)d_in[2];
  const float* v_ws     = (const float*)d_in[3];
  const float* b_ws     = (const float*)d_in[4];
  const float* a_w      = (const float*)d_in[5];
  const float* g_w      = (const float*)d_in[6];
  const float* o_w      = (const float*)d_in[7];
  const float* q_conv_w = (const float*)d_in[8];
  const float* k_conv   = (const float*)d_in[9];
  const float* v_conv   = (const float*)d_in[10];
  const float* A_log    = (const float*)d_in[11];
  const float* dt_bias  = (const float*)d_in[12];
  const float* o_norm_w = (const float*)d_in[13];
  float* out = (float*)d_out;

  char* ws = (char*)d_ws;
  size_t off = 0;
  auto take = [&](size_t bytes) {
    size_t r = off;
    off += (bytes + 255) & ~(size_t)255;
    return r;
  };
  // Persistent buffers
  short* P  = (short*)(ws + take((size_t)NTOK * PJ_N * 2));   // live 3-8
  short* oT = (short*)(ws + take((size_t)2048 * 3072 * 2));   // live 2-9
  // xbf (step 3 only) reused for Mm (steps 6-7)
  size_t regX = take((size_t)NTOK * 2048 * 2);                // 8.39 MB
  short* xbf = (short*)(ws + regX);
  short* Mm  = (short*)(ws + regX);                           // 1.57 MB
  // Region A: WTall (steps 2-3) reused for NTW|Qg|KdT|TBV (steps 6-7)
  size_t regA = take((size_t)PJ_N * 2048 * 2);                // 56,623,104 B
  short* WTall = (short*)(ws + regA);
  short* NTW = (short*)(ws + regA);
  short* Qg  = NTW + (size_t)384 * 16384;
  short* KdT = Qg  + (size_t)384 * 8192;
  short* TBV = KdT + (size_t)384 * 16384;   // ends exactly at regA + 56,623,104
  // Region B: conv outputs (steps 5-6) reused for O/OutPre (steps 7-9)
  size_t regB = take((size_t)44040192);                       // 44.0 MB
  short* Qc  = (short*)(ws + regB);
  short* K0c = Qc  + (size_t)NTOK * 1536;
  short* K1c = K0c + (size_t)NTOK * 1536;
  short* V0c = K1c + (size_t)NTOK * 1536;
  short* V1c = V0c + (size_t)NTOK * 3072;
  short* O      = (short*)(ws + regB);                        // 12.6 MB
  short* OutPre = O + (size_t)NTOK * 6 * 512;                 // 12.6 MB
  float* Beta0 = (float*)(ws + take((size_t)NTOK * 6 * 4));
  float* Beta1 = (float*)(ws + take((size_t)NTOK * 6 * 4));
  float* G     = (float*)(ws + take((size_t)NTOK * 6 * 4));
  float* dCp   = (float*)(ws + take((size_t)384 * 4));
  if (off > ws_size) return;  // ws too small: no-op (diagnosable, capture-safe)

  // 1) convert x to bf16
  cvt_bf16<<<dim3(NTOK * 2048 / 8 / 256), 256, 0, stream>>>(x, xbf, NTOK * 2048);

  // 2) weight transposes (fp32 -> bf16) into WTall [q|k0|k1|v0|v1|gate] and oT
  transpose_w<<<dim3(24), 256, 0, stream>>>(q_w, WTall, 2048, 1536);
  transpose_w<<<dim3(24), 256, 0, stream>>>(k_ws, WTall + (size_t)1536 * 2048, 2048, 1536);
  transpose_w<<<dim3(24), 256, 0, stream>>>(k_ws + (size_t)2048 * 1536, WTall + (size_t)3072 * 2048, 2048, 1536);
  transpose_w<<<dim3(48), 256, 0, stream>>>(v_ws, WTall + (size_t)4608 * 2048, 2048, 3072);
  transpose_w<<<dim3(48), 256, 0, stream>>>(v_ws + (size_t)2048 * 3072, WTall + (size_t)7680 * 2048, 2048, 3072);
  transpose_w<<<dim3(48), 256, 0, stream>>>(g_w, WTall + (size_t)10752 * 2048, 2048, 3072);
  transpose_w<<<dim3(32), 256, 0, stream>>>(o_w, oT, 3072, 2048);

  // 3) fused projection GEMM (XCD-aware 1-D grid, N padded 108->112 tiles)
  gemm_bt<false><<<dim3(16 * 112), 256, 0, stream>>>(
      xbf, WTall, P, NTOK, PJ_N, 2048);

  // 4) beta / g (fp32 inputs straight from d_in)
  proj_small<<<dim3(NTOK), 64, 0, stream>>>(x, b_ws, a_w, A_log, dt_bias, Beta0, Beta1, G);

  // 5) conv + silu (+ l2norm for q/k)
  conv_norm_qk<<<dim3(NTOK, 6), 256, 0, stream>>>(P, q_conv_w, Qc, 0, 0.0625f);
  conv_norm_qk<<<dim3(NTOK, 6), 256, 0, stream>>>(P, k_conv, K0c, 1536, 1.f);
  conv_norm_qk<<<dim3(NTOK, 6), 256, 0, stream>>>(P, k_conv + (size_t)1536 * 4, K1c, 3072, 1.f);
  conv_v<<<dim3(NTOK, 12), 256, 0, stream>>>(P, v_conv, V0c, 4608);
  conv_v<<<dim3(NTOK, 12), 256, 0, stream>>>(P, v_conv + (size_t)3072 * 4, V1c, 7680);

  // 6) chunk operand precompute (WY form)
  precompute_chunk<<<dim3(32, 6, 2), 256, 0, stream>>>(Qc, K0c, K1c, V0c, V1c,
      Beta0, Beta1, G, NTW, Qg, KdT, Mm, TBV, dCp);

  // 7) sequential chunk scan (384 blocks x 2 waves, register operands)
  scan_kernel<<<dim3(384), 128, 0, stream>>>(NTW, Qg, KdT, Mm, TBV, dCp, O);

  // 8) rms-norm * silu(gate)
  rms_gate<<<dim3(NTOK, 6), 256, 0, stream>>>(O, P, o_norm_w, OutPre);

  // 9) output projection (fp32 out)
  gemm_bt<true><<<dim3(16 * 16), 256, 0, stream>>>(
      OutPre, oT, out, NTOK, 2048, 3072);
}

// Round 8
// 1119.649 us; speedup vs baseline: 1.0133x; 1.0133x over previous
//
#include <hip/hip_runtime.h>

// ---------------------------------------------------------------------------
// GatedDeltaProduct: B=2,T=1024,HID=2048, NH=2, H=6, DK=256, DV=512, CHUNK=64
// Inputs fp32, output fp32. Internal bf16 MFMA. WY chunked gated delta rule.
// R9:  precompute_chunk C3 register-resident substitution (394us -> gone).
// R11: counted vmcnt etc. Measured neutral (163us) — loads issued+awaited
//      within the same chunk; nothing hides them.
// R15: 2-wave blocks + reg operands. REGRESSED (183us) — same structural
//      flaw + barrier drains; occupancy alone can't hide per-wave serial
//      load->wait->compute.
// R16: cross-chunk software pipeline (operands of c+1 are precomputed and
//      independent of chunk c's result; only S is the carried dependency):
//   * NTW double-buffered in LDS (2x32KB), staged via gl_lds for c+1 at the
//     TOP of chunk c -> full-chunk latency hiding. Wave-own rows (wave w
//     stages+reads rows 32w..32w+31) so own vmcnt guards own data.
//   * oac (Qg@S0) moved after bar1: Qg/Mm/TBV/KdT issued at top are consumed
//     a phase later -> hidden without register double-buffering.
//   * counted waits: top vmcnt(4) staging done; vmcnt(32) dc/Qg/Mm/TBV done;
//     vmcnt(20) KdT done. Next-chunk idx wraps (c+1)&31 (uniform counts,
//     stale wrap data never consumed).
//   * 3 barriers/chunk; LDS 76.3KB -> 2 blocks/CU, all 384 blocks resident.
// ---------------------------------------------------------------------------

typedef short bf16x8 __attribute__((ext_vector_type(8)));
typedef short bf16x4 __attribute__((ext_vector_type(4)));
typedef float f32x4 __attribute__((ext_vector_type(4)));

__device__ __forceinline__ float bf2f(short s) {
  unsigned u = ((unsigned)(unsigned short)s) << 16;
  float f; __builtin_memcpy(&f, &u, 4); return f;
}
__device__ __forceinline__ short f2bf(float f) {
  unsigned u; __builtin_memcpy(&u, &f, 4);
  u = (u + 0x7FFFu + ((u >> 16) & 1u)) >> 16;
  return (short)u;
}
__device__ __forceinline__ f32x4 MFMA(bf16x8 a, bf16x8 b, f32x4 c) {
  return __builtin_amdgcn_mfma_f32_16x16x32_bf16(a, b, c, 0, 0, 0);
}
// async global->LDS, 16B per lane; lds dest = wave-uniform base + lane*16
__device__ __forceinline__ void gl_lds16(const short* g, short* l) {
  __builtin_amdgcn_global_load_lds(
      (const __attribute__((address_space(1))) unsigned int*)g,
      (__attribute__((address_space(3))) unsigned int*)l, 16, 0, 0);
}

#define PJ_N 13824   // [q 0:1536][k0][k1][v0 4608:][v1 7680:][gate 10752:]
#define NTOK 2048    // B*T rows

// ---------------------------------------------------------------------------
// fp32 -> bf16 bulk convert (for x). n multiple of 8.
__global__ __launch_bounds__(256) void cvt_bf16(
    const float* __restrict__ src, short* __restrict__ dst, int n)
{
  int i = (blockIdx.x * 256 + threadIdx.x) * 8;
  if (i + 8 <= n) {
    float4 a = *(const float4*)(src + i);
    float4 b = *(const float4*)(src + i + 4);
    short v[8] = {f2bf(a.x), f2bf(a.y), f2bf(a.z), f2bf(a.w),
                  f2bf(b.x), f2bf(b.y), f2bf(b.z), f2bf(b.w)};
    uint4 u; __builtin_memcpy(&u, v, 16);
    *(uint4*)(dst + i) = u;
  }
}

// ---------------------------------------------------------------------------
// Weight transpose + convert: W (K x N, fp32) -> WT (N x K, bf16).
__global__ __launch_bounds__(256) void transpose_w(
    const float* __restrict__ W, short* __restrict__ WT, int K, int N)
{
  int lane = threadIdx.x & 63, y = threadIdx.x >> 6;
  int n = blockIdx.x * 64 + lane;
  for (int k0 = y * 8; k0 < K; k0 += 32) {
    short v[8];
    #pragma unroll
    for (int j = 0; j < 8; ++j) v[j] = f2bf(W[(size_t)(k0 + j) * N + n]);
    uint4 u; __builtin_memcpy(&u, v, 16);
    *(uint4*)(WT + (size_t)n * K + k0) = u;
  }
}

// ---------------------------------------------------------------------------
// GEMM: C[M,N] = A[M,K] @ B, given BT (N x K). bf16 in, fp32 accum.
// 1-D grid, XCD-aware. global_load_lds staging, XOR-swizzled LDS.
template<bool F32OUT>
__global__ __launch_bounds__(256) void gemm_bt(
    const short* __restrict__ A, const short* __restrict__ BT,
    void* __restrict__ Cp, int M, int N, int K)
{
  __shared__ short As[128 * 64];
  __shared__ short Bs[128 * 64];
  const int tid = threadIdx.x;
  const int lane = tid & 63, wv = tid >> 6;
  const int quad = lane >> 4, l16 = lane & 15;
  const int j = blockIdx.x;
  const int xcd = j & 7, local = j >> 3;
  const int mtile = local & 15, ng = local >> 4;
  const int ntile = ng * 8 + xcd;
  if (ntile * 128 >= N) return;     // pad blocks no-op (uniform per block)
  const int m0 = mtile * 128, n0 = ntile * 128;
  const int wm = (wv >> 1) * 64, wn = (wv & 1) * 64;
  const int lrow = lane >> 3;              // 0..7 within staging call
  const int lperm = (lane & 7) ^ lrow;     // xor swizzle source segment
  const int xr = l16 & 7;                  // read-side xor key
  f32x4 zz = {0.f, 0.f, 0.f, 0.f};
  f32x4 acc[4][4];
  #pragma unroll
  for (int i = 0; i < 4; ++i)
    #pragma unroll
    for (int jj = 0; jj < 4; ++jj) acc[i][jj] = zz;

  for (int k0 = 0; k0 < K; k0 += 64) {
    __syncthreads();
    #pragma unroll
    for (int c = 0; c < 4; ++c) {
      int row = (wv * 4 + c) * 8 + lrow;
      gl_lds16(A  + (size_t)(m0 + row) * K + k0 + lperm * 8,
               As + (wv * 4 + c) * 512);
      gl_lds16(BT + (size_t)(n0 + row) * K + k0 + lperm * 8,
               Bs + (wv * 4 + c) * 512);
    }
    __syncthreads();
    #pragma unroll
    for (int kk = 0; kk < 64; kk += 32) {
      const int ksb = kk >> 3;
      bf16x8 af[4], bfr[4];
      #pragma unroll
      for (int i = 0; i < 4; ++i)
        af[i] = *(const bf16x8*)(As + (wm + i * 16 + l16) * 64 +
                                 (((ksb + quad) ^ xr) << 3));
      #pragma unroll
      for (int jj = 0; jj < 4; ++jj)
        bfr[jj] = *(const bf16x8*)(Bs + (wn + jj * 16 + l16) * 64 +
                                   (((ksb + quad) ^ xr) << 3));
      #pragma unroll
      for (int i = 0; i < 4; ++i)
        #pragma unroll
        for (int jj = 0; jj < 4; ++jj)
          acc[i][jj] = MFMA(af[i], bfr[jj], acc[i][jj]);
    }
  }
  #pragma unroll
  for (int i = 0; i < 4; ++i)
    #pragma unroll
    for (int jj = 0; jj < 4; ++jj)
      #pragma unroll
      for (int r = 0; r < 4; ++r) {
        int row = m0 + wm + i * 16 + quad * 4 + r;
        int col = n0 + wn + jj * 16 + l16;
        if (F32OUT) ((float*)Cp)[(size_t)row * N + col] = acc[i][jj][r];
        else        ((short*)Cp)[(size_t)row * N + col] = f2bf(acc[i][jj][r]);
      }
}

// ---------------------------------------------------------------------------
// beta (sigmoid(x@b_ws[i])) and g (-exp(A_log)*softplus(x@a_w+dt_bias)).
__global__ __launch_bounds__(64) void proj_small(
    const float* __restrict__ x, const float* __restrict__ b_ws,
    const float* __restrict__ a_w, const float* __restrict__ A_log,
    const float* __restrict__ dt_bias,
    float* __restrict__ Beta0, float* __restrict__ Beta1, float* __restrict__ G)
{
  int row = blockIdx.x, lane = threadIdx.x;
  float p[18];
  #pragma unroll
  for (int j = 0; j < 18; ++j) p[j] = 0.f;
  for (int k = lane; k < 2048; k += 64) {
    float xv = x[(size_t)row * 2048 + k];
    const float* b0 = b_ws + (size_t)k * 6;
    const float* b1 = b_ws + (size_t)2048 * 6 + (size_t)k * 6;
    const float* aw = a_w + (size_t)k * 6;
    #pragma unroll
    for (int j = 0; j < 6; ++j) {
      p[j]      += xv * b0[j];
      p[6 + j]  += xv * b1[j];
      p[12 + j] += xv * aw[j];
    }
  }
  #pragma unroll
  for (int j = 0; j < 18; ++j) {
    #pragma unroll
    for (int off = 32; off > 0; off >>= 1)
      p[j] += __shfl_down(p[j], off);
  }
  if (lane == 0) {
    #pragma unroll
    for (int j = 0; j < 6; ++j) {
      Beta0[(size_t)row * 6 + j] = 1.f / (1.f + expf(-p[j]));
      Beta1[(size_t)row * 6 + j] = 1.f / (1.f + expf(-p[6 + j]));
      float z = p[12 + j] + dt_bias[j];
      float sp = (z > 15.f) ? z : log1pf(expf(z));
      G[(size_t)row * 6 + j] = -expf(A_log[j]) * sp;
    }
  }
}

// ---------------------------------------------------------------------------
// Conv(K=4 causal, depthwise) + SiLU + per-head l2norm (q/k). grid (2048, 6).
__global__ __launch_bounds__(256) void conv_norm_qk(
    const short* __restrict__ P, const float* __restrict__ convw,
    short* __restrict__ dst, int colofs, float scale)
{
  __shared__ float red[256];
  int c = threadIdx.x, h = blockIdx.y, row = blockIdx.x;
  int t = row & 1023;
  int ch = colofs + h * 256 + c;
  const float* cw = convw + (size_t)(h * 256 + c) * 4;
  float acc = 0.f;
  #pragma unroll
  for (int j = 0; j < 4; ++j) {
    int tt = t - 3 + j;
    if (tt >= 0) acc += bf2f(P[(size_t)(row - 3 + j) * PJ_N + ch]) * cw[j];
  }
  float y = acc / (1.f + expf(-acc));   // silu
  red[c] = y * y;
  __syncthreads();
  for (int s = 128; s > 0; s >>= 1) {
    if (c < s) red[c] += red[c + s];
    __syncthreads();
  }
  float nrm = rsqrtf(red[0] + 1e-12f) * scale;
  dst[((size_t)row * 6 + h) * 256 + c] = f2bf(y * nrm);
}

// Conv + SiLU for v. grid (2048, 12).
__global__ __launch_bounds__(256) void conv_v(
    const short* __restrict__ P, const float* __restrict__ convw,
    short* __restrict__ dst, int colofs)
{
  int cg = blockIdx.y * 256 + threadIdx.x;
  int row = blockIdx.x;
  int t = row & 1023;
  const float* cw = convw + (size_t)cg * 4;
  float acc = 0.f;
  #pragma unroll
  for (int j = 0; j < 4; ++j) {
    int tt = t - 3 + j;
    if (tt >= 0) acc += bf2f(P[(size_t)(row - 3 + j) * PJ_N + colofs + cg]) * cw[j];
  }
  float y = acc / (1.f + expf(-acc));
  dst[(size_t)row * 3072 + cg] = f2bf(y);
}

// ---------------------------------------------------------------------------
// Per-(b,h,chunk) precompute of WY operands. grid (32, 6, 2), block 256.
// Qg/Mm store only odd interleaved rows (32 per chunk).
// TBV stored TRANSPOSED: [v_full=512][t=64] (R11, for b64 loads in scan).
#define KBLD 264
#define R2LD 72
#define WTLD 72
__global__ __launch_bounds__(256) void precompute_chunk(
    const short* __restrict__ Qc, const short* __restrict__ K0c, const short* __restrict__ K1c,
    const short* __restrict__ V0c, const short* __restrict__ V1c,
    const float* __restrict__ Beta0, const float* __restrict__ Beta1, const float* __restrict__ G,
    short* __restrict__ NTW, short* __restrict__ Qg, short* __restrict__ KdT,
    short* __restrict__ Mm, short* __restrict__ TBV, float* __restrict__ dC)
{
  __shared__ short r0[256 * 72];   // kb (64 x KBLD) -> wt (256 x WTLD) -> BVT
  __shared__ float Xs[64 * 64];    // A matrix (f32), consumed by substitution
  __shared__ short r2[64 * 72];    // KK^T (bf16) -> X (bf16)
  const int tid = threadIdx.x;
  const int lane = tid & 63, wv = tid >> 6;
  const int quad = lane >> 4, l16 = lane & 15;
  const int c = blockIdx.x, h = blockIdx.y, b = blockIdx.z;
  const int i0 = c * 32;
  const size_t idx = (size_t)((b * 6 + h) * 32 + c);
  short* kb = r0;
  f32x4 zz = {0.f, 0.f, 0.f, 0.f};
  bf16x8 z8 = {0, 0, 0, 0, 0, 0, 0, 0};

  // per-lane g/beta for interleaved position t = lane; wave-prefix cumsum
  float gv, betaL;
  {
    int t = lane, par = t & 1, i = i0 + (t >> 1);
    size_t gofs = (size_t)(b * 1024 + i) * 6 + h;
    gv = par ? 0.f : G[gofs];
    betaL = par ? Beta1[gofs] : Beta0[gofs];
  }
  float cum = gv;
  #pragma unroll
  for (int off = 1; off < 64; off <<= 1) {
    float nb = __shfl_up(cum, off);
    if (lane >= off) cum += nb;
  }
  float c63 = __shfl(cum, 63);
  float eBt = expf(cum);          // exp(B_t)
  float eRem = expf(c63 - cum);   // exp(B63 - B_t)
  float wsc = betaL * eBt;        // beta_t exp(B_t)
  if (tid == 0) dC[idx] = expf(c63);

  // stage k chunk (interleaved parities) into kb
  {
    int row = tid >> 2, seg = (tid & 3) * 64;
    int par = row & 1, i = i0 + (row >> 1);
    const short* src = (par ? K1c : K0c) + ((size_t)(b * 1024 + i) * 6 + h) * 256 + seg;
    short* dp = kb + row * KBLD + seg;
    #pragma unroll
    for (int e = 0; e < 64; e += 8)
      *(uint4*)(dp + e) = *(const uint4*)(src + e);
  }
  __syncthreads();

  // KK^T (bf16 into r2). wave = t row-tile.
  {
    f32x4 acc[4];
    #pragma unroll
    for (int ts = 0; ts < 4; ++ts) acc[ts] = zz;
    #pragma unroll
    for (int ks = 0; ks < 8; ++ks) {
      bf16x8 af = *(const bf16x8*)(kb + (wv * 16 + l16) * KBLD + ks * 32 + quad * 8);
      #pragma unroll
      for (int ts = 0; ts < 4; ++ts) {
        bf16x8 bfv = *(const bf16x8*)(kb + (ts * 16 + l16) * KBLD + ks * 32 + quad * 8);
        acc[ts] = MFMA(af, bfv, acc[ts]);
      }
    }
    #pragma unroll
    for (int ts = 0; ts < 4; ++ts)
      #pragma unroll
      for (int r = 0; r < 4; ++r)
        r2[(wv * 16 + quad * 4 + r) * R2LD + ts * 16 + l16] = f2bf(acc[ts][r]);
  }
  // QK^T -> M (masked, decayed; odd rows only) directly to global
  {
    f32x4 acc[4];
    #pragma unroll
    for (int ts = 0; ts < 4; ++ts) acc[ts] = zz;
    int t_row = wv * 16 + l16;
    int podd = t_row & 1, iq = i0 + (t_row >> 1);
    const short* qrow = Qc + ((size_t)(b * 1024 + iq) * 6 + h) * 256;
    #pragma unroll
    for (int ks = 0; ks < 8; ++ks) {
      bf16x8 af = z8;
      if (podd) af = *(const bf16x8*)(qrow + ks * 32 + quad * 8);
      #pragma unroll
      for (int ts = 0; ts < 4; ++ts) {
        bf16x8 bfv = *(const bf16x8*)(kb + (ts * 16 + l16) * KBLD + ks * 32 + quad * 8);
        acc[ts] = MFMA(af, bfv, acc[ts]);
      }
    }
    short* Mp = Mm + idx * 2048;
    #pragma unroll
    for (int ts = 0; ts < 4; ++ts)
      #pragma unroll
      for (int r = 1; r < 4; r += 2) {       // odd rows only
        int t = wv * 16 + quad * 4 + r, s = ts * 16 + l16;
        float ct = __shfl(cum, t), cs = __shfl(cum, s);
        float v = (s <= t) ? acc[ts][r] * expf(ct - cs) : 0.f;
        Mp[(t >> 1) * 64 + s] = f2bf(v);
      }
  }
  // Qg (odd rows only): Qg[th][d] = exp(B_{2th+1}) q_{2th+1}[d]
  {
    int th = tid >> 3, dseg = (tid & 7) * 32;
    int t = th * 2 + 1;
    float sc = __shfl(eBt, t);
    const short* qrow = Qc + ((size_t)(b * 1024 + i0 + th) * 6 + h) * 256 + dseg;
    short* qgp = Qg + idx * 8192 + (size_t)th * 256 + dseg;
    #pragma unroll
    for (int e = 0; e < 32; e += 8) {
      bf16x8 v = *(const bf16x8*)(qrow + e);
      bf16x8 w;
      #pragma unroll
      for (int q2 = 0; q2 < 8; ++q2) w[q2] = f2bf(bf2f(v[q2]) * sc);
      *(bf16x8*)(qgp + e) = w;
    }
  }
  // KdT[d][t] = exp(B63-B_t) k_t[d]
  {
    int d = tid;
    short buf[64];
    #pragma unroll
    for (int t = 0; t < 64; ++t) {
      float sc = __shfl(eRem, t);
      buf[t] = f2bf(bf2f(kb[t * KBLD + d]) * sc);
    }
    short* kp = KdT + idx * 16384 + (size_t)d * 64;
    #pragma unroll
    for (int e = 0; e < 64; e += 8) {
      uint4 v; __builtin_memcpy(&v, buf + e, 16);
      *(uint4*)(kp + e) = v;
    }
  }
  __syncthreads();

  // C1: cache kb column d = tid in registers
  short colv[64];
  {
    int d = tid;
    #pragma unroll
    for (int t = 0; t < 64; ++t) colv[t] = kb[t * KBLD + d];
  }
  // A precompute (parallel, all 256 threads): Xs[t][s] = beta_t exp(ct-cs)
  // KKT[t][s] for s<t else 0. Per iteration t is wave-uniform; s == lane, so
  // cs needs no shuffle at all.
  #pragma unroll
  for (int k = 0; k < 16; ++k) {
    int t = wv + k * 4;
    float bt = __shfl(betaL, t);
    float ct = __shfl(cum, t);
    float a = (lane < t) ? bt * expf(ct - cum) * bf2f(r2[t * R2LD + lane]) : 0.f;
    Xs[t * 64 + lane] = a;
  }
  __syncthreads();
  // C2: wt[d][s] = beta_s exp(B_s) k_s[d] (over r0)
  {
    int d = tid;
    short wrow[64];
    #pragma unroll
    for (int s = 0; s < 64; ++s) wrow[s] = f2bf(bf2f(colv[s]) * __shfl(wsc, s));
    short* wp = r0 + d * WTLD;
    #pragma unroll
    for (int e = 0; e < 64; e += 8) {
      uint4 v; __builtin_memcpy(&v, wrow + e, 16);
      *(uint4*)(wp + e) = v;
    }
  }
  // C3: wave0 solves X = (I+A)^-1 by forward substitution, column j = lane,
  // X entirely in registers (static triangular unroll; A read as broadcast
  // float2 from LDS). Writes bf16 X directly into r2.
  if (wv == 0) {
    const int j = lane;
    float xcol[64];
    #pragma unroll
    for (int t = 0; t < 64; ++t) {
      float sa0 = 0.f, sa1 = 0.f;
      const float2* ap = (const float2*)(Xs + t * 64);
      #pragma unroll
      for (int s = 0; s + 1 < t; s += 2) {
        float2 av = ap[s >> 1];
        sa0 += av.x * xcol[s];
        sa1 += av.y * xcol[s + 1];
      }
      if (t & 1) sa0 += Xs[t * 64 + (t - 1)] * xcol[t - 1];
      float xv = ((t == j) ? 1.f : 0.f) - (sa0 + sa1);
      xcol[t] = xv;
      r2[t * R2LD + j] = f2bf(xv);
    }
  }
  __syncthreads();
  // NTW = -(X @ W)
  {
    f32x4 acc[4][4];
    #pragma unroll
    for (int i = 0; i < 4; ++i)
      #pragma unroll
      for (int j = 0; j < 4; ++j) acc[i][j] = zz;
    #pragma unroll
    for (int ks = 0; ks < 2; ++ks) {
      bf16x8 af[4], bfv[4];
      #pragma unroll
      for (int tt = 0; tt < 4; ++tt)
        af[tt] = *(const bf16x8*)(r2 + (tt * 16 + l16) * R2LD + ks * 32 + quad * 8);
      #pragma unroll
      for (int dt = 0; dt < 4; ++dt)
        bfv[dt] = *(const bf16x8*)(r0 + ((wv * 4 + dt) * 16 + l16) * WTLD + ks * 32 + quad * 8);
      #pragma unroll
      for (int tt = 0; tt < 4; ++tt)
        #pragma unroll
        for (int dt = 0; dt < 4; ++dt)
          acc[tt][dt] = MFMA(af[tt], bfv[dt], acc[tt][dt]);
    }
    short* np = NTW + idx * 16384;
    #pragma unroll
    for (int tt = 0; tt < 4; ++tt)
      #pragma unroll
      for (int dt = 0; dt < 4; ++dt)
        #pragma unroll
        for (int r = 0; r < 4; ++r) {
          int t = tt * 16 + quad * 4 + r, d = (wv * 4 + dt) * 16 + l16;
          np[t * 256 + d] = f2bf(-acc[tt][dt][r]);
        }
  }
  __syncthreads();
  // TBV = X @ (beta*v), two DV halves through r0; stored [v_full][t] (b64)
  for (int vh = 0; vh < 2; ++vh) {
    {
      int vl = tid;
      short bv[64];
      #pragma unroll
      for (int t = 0; t < 64; ++t) {
        int par = t & 1, i = i0 + (t >> 1);
        const short* src = (par ? V1c : V0c) + (size_t)(b * 1024 + i) * 3072 + h * 512 + vh * 256 + vl;
        bv[t] = f2bf(bf2f(*src) * __shfl(betaL, t));
      }
      short* bp = r0 + vl * WTLD;
      #pragma unroll
      for (int e = 0; e < 64; e += 8) {
        uint4 v; __builtin_memcpy(&v, bv + e, 16);
        *(uint4*)(bp + e) = v;
      }
    }
    __syncthreads();
    {
      f32x4 acc[4][4];
      #pragma unroll
      for (int i = 0; i < 4; ++i)
        #pragma unroll
        for (int j = 0; j < 4; ++j) acc[i][j] = zz;
      #pragma unroll
      for (int ks = 0; ks < 2; ++ks) {
        bf16x8 af[4], bfv[4];
        #pragma unroll
        for (int tt = 0; tt < 4; ++tt)
          af[tt] = *(const bf16x8*)(r2 + (tt * 16 + l16) * R2LD + ks * 32 + quad * 8);
        #pragma unroll
        for (int vt = 0; vt < 4; ++vt)
          bfv[vt] = *(const bf16x8*)(r0 + ((wv * 4 + vt) * 16 + l16) * WTLD + ks * 32 + quad * 8);
        #pragma unroll
        for (int tt = 0; tt < 4; ++tt)
          #pragma unroll
          for (int vt = 0; vt < 4; ++vt)
            acc[tt][vt] = MFMA(af[tt], bfv[vt], acc[tt][vt]);
      }
      short* tp = TBV + idx * 32768;
      #pragma unroll
      for (int tt = 0; tt < 4; ++tt)
        #pragma unroll
        for (int vt = 0; vt < 4; ++vt) {
          // D frag: row = t = tt*16+quad*4+r, col = v = (wv*4+vt)*16+l16
          int vfull = vh * 256 + (wv * 4 + vt) * 16 + l16;
          int t0 = tt * 16 + quad * 4;
          short w[4];
          #pragma unroll
          for (int r = 0; r < 4; ++r) w[r] = f2bf(acc[tt][vt][r]);
          uint2 uv; __builtin_memcpy(&uv, w, 8);
          *(uint2*)(tp + (size_t)vfull * 64 + t0) = uv;
        }
    }
    __syncthreads();
  }
}

// ---------------------------------------------------------------------------
// Scan: 2-wave blocks (128 thr) per (b,h,16-col DV slice). grid 384.
// R16: cross-chunk pipeline. NTW dbuf in LDS staged one chunk ahead
// (wave-own rows); Qg/Mm/TBV/KdT issued at top, consumed a phase later.
// 3 barriers/chunk. Counted vmcnt(4/32/20).
#define SLD 264
#define ULD 72
__global__ __launch_bounds__(128) void scan_kernel(
    const short* __restrict__ NTW, const short* __restrict__ Qg,
    const short* __restrict__ KdT, const short* __restrict__ Mm,
    const short* __restrict__ TBV, const float* __restrict__ dC,
    short* __restrict__ O)
{
  __shared__ short NTWs[2][64 * 256]; // 64KB dbuf, LDS[t][s]=G[t][s^(t&7)]
  __shared__ short S[16 * SLD];       // state slice [v_local][d], bf16
  __shared__ short U[16 * ULD];       // u slice [v_local][t], bf16
  const int tid = threadIdx.x;
  const int lane = tid & 63, w = tid >> 6;
  const int quad = lane >> 4, l16 = lane & 15;
  const int xk = l16 & 7;           // read-side xor key
  const int r2l = lane >> 5;        // staging: row within pair
  const int s32 = lane & 31;        // staging: 16B seg 0..31
  // XCD-aware swizzle (bijective, 384 = 8 xcd * 48)
  const int gid = (blockIdx.x & 7) * 48 + (blockIdx.x >> 3);
  const int bh = gid >> 5, slice = gid & 31;
  const int b = bh / 6, h = bh % 6;
  const int vbase = slice * 16;
  f32x4 zz = {0.f, 0.f, 0.f, 0.f};
  for (int e = tid; e < 16 * SLD; e += 128) S[e] = 0;

  // prologue: stage chunk 0 NTW (own rows) into buf0, full drain
  {
    const short* ntw0 = NTW + (size_t)(bh * 32) * 16384;
    #pragma unroll
    for (int j = 0; j < 16; ++j) {
      int row = 32 * w + 2 * j + r2l;
      gl_lds16(ntw0 + (size_t)row * 256 + ((s32 ^ (row & 7)) << 3),
               &NTWs[0][(32 * w + 2 * j) * 256]);
    }
  }
  __syncthreads();   // drains vmcnt+lgkm: staging-0 + S init visible

  for (int c = 0; c < 32; ++c) {
    size_t idx = (size_t)(bh * 32 + c);
    const short* qg  = Qg  + idx * 8192;
    const short* kdt = KdT + idx * 16384;
    const short* mp  = Mm  + idx * 2048;
    const short* tb  = TBV + idx * 32768;
    short* bufC = &NTWs[c & 1][0];
    short* bufN = &NTWs[(c & 1) ^ 1][0];
    const int cn = (c + 1) & 31;   // wrap: uniform counts, never consumed stale
    const short* ntwN = NTW + (size_t)(bh * 32 + cn) * 16384;

    // top wait: staging for THIS chunk landed (<=4 older O-stores remain)
    asm volatile("s_waitcnt vmcnt(4)" ::: "memory");
    __builtin_amdgcn_sched_barrier(0);

    // reg loads for c: dc, Qg(8), Mm(2), TBV(2), KdT(16)
    float dc = dC[idx];
    bf16x8 qgr[8];
    #pragma unroll
    for (int ks = 0; ks < 8; ++ks)
      qgr[ks] = *(const bf16x8*)(
          qg + (size_t)(w * 16 + l16) * 256 + ks * 32 + quad * 8);
    bf16x8 mmr2[2];
    #pragma unroll
    for (int ks = 0; ks < 2; ++ks)
      mmr2[ks] = *(const bf16x8*)(mp + (w * 16 + l16) * 64 + ks * 32 + quad * 8);
    bf16x4 tbv2[2];
    #pragma unroll
    for (int j = 0; j < 2; ++j)
      tbv2[j] = *(const bf16x4*)(
          tb + (size_t)(vbase + l16) * 64 + (2 * w + j) * 16 + quad * 4);
    bf16x8 kdr2[2][2][4];
    #pragma unroll
    for (int j = 0; j < 2; ++j)
      #pragma unroll
      for (int ks = 0; ks < 2; ++ks)
        #pragma unroll
        for (int dt = 0; dt < 4; ++dt)
          kdr2[j][ks][dt] = *(const bf16x8*)(
              kdt + (size_t)(((2 * w + j) * 4 + dt) * 16 + l16) * 64 + ks * 32 + quad * 8);
    __builtin_amdgcn_sched_barrier(0);

    // issue staging for NEXT chunk into bufN (own rows, 16 gl_lds)
    #pragma unroll
    for (int j = 0; j < 16; ++j) {
      int row = 32 * w + 2 * j + r2l;
      gl_lds16(ntwN + (size_t)row * 256 + ((s32 ^ (row & 7)) << 3),
               bufN + (32 * w + 2 * j) * 256);
    }
    __builtin_amdgcn_sched_barrier(0);

    // --- phase 1: uac = NTW@S0 (own 2 tiles) ---
    f32x4 uac2[2];
    uac2[0] = zz; uac2[1] = zz;
    __builtin_amdgcn_s_setprio(1);
    #pragma unroll
    for (int ks = 0; ks < 8; ++ks) {
      bf16x8 bfv = *(const bf16x8*)(S + l16 * SLD + ks * 32 + quad * 8);
      int gx = ks * 4 + quad;
      bf16x8 af0 = *(const bf16x8*)(bufC + ((2 * w + 0) * 16 + l16) * 256 + ((gx ^ xk) << 3));
      bf16x8 af1 = *(const bf16x8*)(bufC + ((2 * w + 1) * 16 + l16) * 256 + ((gx ^ xk) << 3));
      uac2[0] = MFMA(af0, bfv, uac2[0]);
      uac2[1] = MFMA(af1, bfv, uac2[1]);
    }
    __builtin_amdgcn_s_setprio(0);

    // dc/Qg/Mm/TBV done (KdT 16 + staging 16 may remain in flight)
    asm volatile("s_waitcnt vmcnt(32)" ::: "memory");
    __builtin_amdgcn_sched_barrier(0);

    // --- u = uac + TBV -> U (own tiles, b64 writes) ---
    #pragma unroll
    for (int j = 0; j < 2; ++j) {
      short wb[4];
      #pragma unroll
      for (int r = 0; r < 4; ++r) wb[r] = f2bf(uac2[j][r] + bf2f(tbv2[j][r]));
      uint2 uv; __builtin_memcpy(&uv, wb, 8);
      *(uint2*)(U + l16 * ULD + (2 * w + j) * 16 + quad * 4) = uv;
    }
    // bar1: U complete, phase1 S reads retired
    asm volatile("s_waitcnt lgkmcnt(0)" ::: "memory");
    __builtin_amdgcn_s_barrier();
    __builtin_amdgcn_sched_barrier(0);

    // --- oac = Qg @ S0 + M @ u (own tile) ---
    f32x4 oac = zz;
    #pragma unroll
    for (int ks = 0; ks < 8; ++ks) {
      bf16x8 bfv = *(const bf16x8*)(S + l16 * SLD + ks * 32 + quad * 8);
      oac = MFMA(qgr[ks], bfv, oac);
    }
    #pragma unroll
    for (int ks = 0; ks < 2; ++ks) {
      bf16x8 bfv = *(const bf16x8*)(U + l16 * ULD + ks * 32 + quad * 8);
      oac = MFMA(mmr2[ks], bfv, oac);
    }

    // --- O store (4 stores; may stay in flight across chunk boundary) ---
    #pragma unroll
    for (int r = 0; r < 4; ++r) {
      int th = w * 16 + quad * 4 + r;
      int i = c * 32 + th;
      O[((size_t)(b * 1024 + i) * 6 + h) * 512 + vbase + l16] = f2bf(oac[r]);
    }

    // KdT done (staging 16 + stores 4 may remain)
    asm volatile("s_waitcnt vmcnt(20)" ::: "memory");
    __builtin_amdgcn_sched_barrier(0);

    // bar2: both waves' oac S0-reads retired before S-phase overwrites S
    asm volatile("s_waitcnt lgkmcnt(0)" ::: "memory");
    __builtin_amdgcn_s_barrier();
    __builtin_amdgcn_sched_barrier(0);

    // --- S1 = dc * S0 + KdT @ u (own g2 halves, b64 S reads/writes) ---
    __builtin_amdgcn_s_setprio(1);
    #pragma unroll
    for (int j = 0; j < 2; ++j) {
      const int g2 = 2 * w + j;
      f32x4 sac[4];
      #pragma unroll
      for (int dt = 0; dt < 4; ++dt) {
        bf16x4 sv = *(const bf16x4*)(S + l16 * SLD + (g2 * 4 + dt) * 16 + quad * 4);
        #pragma unroll
        for (int r = 0; r < 4; ++r) sac[dt][r] = dc * bf2f(sv[r]);
      }
      #pragma unroll
      for (int ks = 0; ks < 2; ++ks) {
        bf16x8 bfv = *(const bf16x8*)(U + l16 * ULD + ks * 32 + quad * 8);
        #pragma unroll
        for (int dt = 0; dt < 4; ++dt)
          sac[dt] = MFMA(kdr2[j][ks][dt], bfv, sac[dt]);
      }
      #pragma unroll
      for (int dt = 0; dt < 4; ++dt) {
        short wb[4];
        #pragma unroll
        for (int r = 0; r < 4; ++r) wb[r] = f2bf(sac[dt][r]);
        uint2 uv; __builtin_memcpy(&uv, wb, 8);
        *(uint2*)(S + l16 * SLD + (g2 * 4 + dt) * 16 + quad * 4) = uv;
      }
    }
    __builtin_amdgcn_s_setprio(0);
    // bar3: S complete for next chunk's phase1/oac
    asm volatile("s_waitcnt lgkmcnt(0)" ::: "memory");
    __builtin_amdgcn_s_barrier();
    __builtin_amdgcn_sched_barrier(0);
  }
}

// ---------------------------------------------------------------------------
// RMS-norm over DV per (b,t,h), times silu(gate). grid (2048, 6).
__global__ __launch_bounds__(256) void rms_gate(
    const short* __restrict__ O, const short* __restrict__ P,
    const float* __restrict__ onw, short* __restrict__ OutPre)
{
  __shared__ float red[256];
  int tid = threadIdx.x, h = blockIdx.y, row = blockIdx.x;
  size_t base = ((size_t)row * 6 + h) * 512;
  float a = bf2f(O[base + tid]), b2 = bf2f(O[base + 256 + tid]);
  red[tid] = a * a + b2 * b2;
  __syncthreads();
  for (int s = 128; s > 0; s >>= 1) {
    if (tid < s) red[tid] += red[tid + s];
    __syncthreads();
  }
  float r = rsqrtf(red[0] * (1.f / 512.f) + 1e-5f);
  #pragma unroll
  for (int half = 0; half < 2; ++half) {
    int col = tid + half * 256;
    float ov = half ? b2 : a;
    float g = bf2f(P[(size_t)row * PJ_N + 10752 + h * 512 + col]);
    float sg = g / (1.f + expf(-g));
    OutPre[(size_t)row * 3072 + h * 512 + col] = f2bf(ov * r * onw[col] * sg);
  }
}

// ---------------------------------------------------------------------------
extern "C" void kernel_launch(void* const* d_in, const int* in_sizes, int n_in,
                              void* d_out, int out_size, void* d_ws, size_t ws_size,
                              hipStream_t stream) {
  const float* x        = (const float*)d_in[0];
  const float* q_w      = (const float*)d_in[1];
  const float* k_ws     = (const float*)d_in[2];
  const float* v_ws     = (const float*)d_in[3];
  const float* b_ws     = (const float*)d_in[4];
  const float* a_w      = (const float*)d_in[5];
  const float* g_w      = (const float*)d_in[6];
  const float* o_w      = (const float*)d_in[7];
  const float* q_conv_w = (const float*)d_in[8];
  const float* k_conv   = (const float*)d_in[9];
  const float* v_conv   = (const float*)d_in[10];
  const float* A_log    = (const float*)d_in[11];
  const float* dt_bias  = (const float*)d_in[12];
  const float* o_norm_w = (const float*)d_in[13];
  float* out = (float*)d_out;

  char* ws = (char*)d_ws;
  size_t off = 0;
  auto take = [&](size_t bytes) {
    size_t r = off;
    off += (bytes + 255) & ~(size_t)255;
    return r;
  };
  // Persistent buffers
  short* P  = (short*)(ws + take((size_t)NTOK * PJ_N * 2));   // live 3-8
  short* oT = (short*)(ws + take((size_t)2048 * 3072 * 2));   // live 2-9
  // xbf (step 3 only) reused for Mm (steps 6-7)
  size_t regX = take((size_t)NTOK * 2048 * 2);                // 8.39 MB
  short* xbf = (short*)(ws + regX);
  short* Mm  = (short*)(ws + regX);                           // 1.57 MB
  // Region A: WTall (steps 2-3) reused for NTW|Qg|KdT|TBV (steps 6-7)
  size_t regA = take((size_t)PJ_N * 2048 * 2);                // 56,623,104 B
  short* WTall = (short*)(ws + regA);
  short* NTW = (short*)(ws + regA);
  short* Qg  = NTW + (size_t)384 * 16384;
  short* KdT = Qg  + (size_t)384 * 8192;
  short* TBV = KdT + (size_t)384 * 16384;   // ends exactly at regA + 56,623,104
  // Region B: conv outputs (steps 5-6) reused for O/OutPre (steps 7-9)
  size_t regB = take((size_t)44040192);                       // 44.0 MB
  short* Qc  = (short*)(ws + regB);
  short* K0c = Qc  + (size_t)NTOK * 1536;
  short* K1c = K0c + (size_t)NTOK * 1536;
  short* V0c = K1c + (size_t)NTOK * 1536;
  short* V1c = V0c + (size_t)NTOK * 3072;
  short* O      = (short*)(ws + regB);                        // 12.6 MB
  short* OutPre = O + (size_t)NTOK * 6 * 512;                 // 12.6 MB
  float* Beta0 = (float*)(ws + take((size_t)NTOK * 6 * 4));
  float* Beta1 = (float*)(ws + take((size_t)NTOK * 6 * 4));
  float* G     = (float*)(ws + take((size_t)NTOK * 6 * 4));
  float* dCp   = (float*)(ws + take((size_t)384 * 4));
  if (off > ws_size) return;  // ws too small: no-op (diagnosable, capture-safe)

  // 1) convert x to bf16
  cvt_bf16<<<dim3(NTOK * 2048 / 8 / 256), 256, 0, stream>>>(x, xbf, NTOK * 2048);

  // 2) weight transposes (fp32 -> bf16) into WTall [q|k0|k1|v0|v1|gate] and oT
  transpose_w<<<dim3(24), 256, 0, stream>>>(q_w, WTall, 2048, 1536);
  transpose_w<<<dim3(24), 256, 0, stream>>>(k_ws, WTall + (size_t)1536 * 2048, 2048, 1536);
  transpose_w<<<dim3(24), 256, 0, stream>>>(k_ws + (size_t)2048 * 1536, WTall + (size_t)3072 * 2048, 2048, 1536);
  transpose_w<<<dim3(48), 256, 0, stream>>>(v_ws, WTall + (size_t)4608 * 2048, 2048, 3072);
  transpose_w<<<dim3(48), 256, 0, stream>>>(v_ws + (size_t)2048 * 3072, WTall + (size_t)7680 * 2048, 2048, 3072);
  transpose_w<<<dim3(48), 256, 0, stream>>>(g_w, WTall + (size_t)10752 * 2048, 2048, 3072);
  transpose_w<<<dim3(32), 256, 0, stream>>>(o_w, oT, 3072, 2048);

  // 3) fused projection GEMM (XCD-aware 1-D grid, N padded 108->112 tiles)
  gemm_bt<false><<<dim3(16 * 112), 256, 0, stream>>>(
      xbf, WTall, P, NTOK, PJ_N, 2048);

  // 4) beta / g (fp32 inputs straight from d_in)
  proj_small<<<dim3(NTOK), 64, 0, stream>>>(x, b_ws, a_w, A_log, dt_bias, Beta0, Beta1, G);

  // 5) conv + silu (+ l2norm for q/k)
  conv_norm_qk<<<dim3(NTOK, 6), 256, 0, stream>>>(P, q_conv_w, Qc, 0, 0.0625f);
  conv_norm_qk<<<dim3(NTOK, 6), 256, 0, stream>>>(P, k_conv, K0c, 1536, 1.f);
  conv_norm_qk<<<dim3(NTOK, 6), 256, 0, stream>>>(P, k_conv + (size_t)1536 * 4, K1c, 3072, 1.f);
  conv_v<<<dim3(NTOK, 12), 256, 0, stream>>>(P, v_conv, V0c, 4608);
  conv_v<<<dim3(NTOK, 12), 256, 0, stream>>>(P, v_conv + (size_t)3072 * 4, V1c, 7680);

  // 6) chunk operand precompute (WY form)
  precompute_chunk<<<dim3(32, 6, 2), 256, 0, stream>>>(Qc, K0c, K1c, V0c, V1c,
      Beta0, Beta1, G, NTW, Qg, KdT, Mm, TBV, dCp);

  // 7) sequential chunk scan (384 blocks x 2 waves, cross-chunk pipeline)
  scan_kernel<<<dim3(384), 128, 0, stream>>>(NTW, Qg, KdT, Mm, TBV, dCp, O);

  // 8) rms-norm * silu(gate)
  rms_gate<<<dim3(NTOK, 6), 256, 0, stream>>>(O, P, o_norm_w, OutPre);

  // 9) output projection (fp32 out)
  gemm_bt<true><<<dim3(16 * 16), 256, 0, stream>>>(
      OutPre, oT, out, NTOK, 2048, 3072);
}

// Round 9
// 804.944 us; speedup vs baseline: 1.4095x; 1.3910x over previous
//
#include <hip/hip_runtime.h>

// ---------------------------------------------------------------------------
// GatedDeltaProduct: B=2,T=1024,HID=2048, NH=2, H=6, DK=256, DV=512, CHUNK=64
// Inputs fp32, output fp32. Internal bf16 MFMA. WY chunked gated delta rule.
// R9:  precompute_chunk C3 register-resident substitution (394us -> gone).
// R11: counted vmcnt etc (163us). R15: 2-wave (183us, regressed).
// R16: cross-chunk pipeline (168us). All three: MfmaUtil ~4%, no spills
//      (WRITE==O exactly), FETCH==footprint -> stall is latency; remaining
//      candidate = dependent-MFMA chain depth (8-10 serial accumulates).
// R17: (a) transpose_w rewritten as LDS-tiled 64x64 (old version: 16B/lane
//      at 4KB stride = 64 line-transactions per store instr on a 24-48
//      block grid; est 40-80us across 7 launches). New: coalesced reads,
//      full-line writes, 768-1536 blocks.
//      (b) scan phase1/oac accumulator chains split 2-way (8-deep -> 2x4,
//      10-deep -> 2x5) — discriminating test of the dep-latency hypothesis.
// ---------------------------------------------------------------------------

typedef short bf16x8 __attribute__((ext_vector_type(8)));
typedef short bf16x4 __attribute__((ext_vector_type(4)));
typedef float f32x4 __attribute__((ext_vector_type(4)));

__device__ __forceinline__ float bf2f(short s) {
  unsigned u = ((unsigned)(unsigned short)s) << 16;
  float f; __builtin_memcpy(&f, &u, 4); return f;
}
__device__ __forceinline__ short f2bf(float f) {
  unsigned u; __builtin_memcpy(&u, &f, 4);
  u = (u + 0x7FFFu + ((u >> 16) & 1u)) >> 16;
  return (short)u;
}
__device__ __forceinline__ f32x4 MFMA(bf16x8 a, bf16x8 b, f32x4 c) {
  return __builtin_amdgcn_mfma_f32_16x16x32_bf16(a, b, c, 0, 0, 0);
}
// async global->LDS, 16B per lane; lds dest = wave-uniform base + lane*16
__device__ __forceinline__ void gl_lds16(const short* g, short* l) {
  __builtin_amdgcn_global_load_lds(
      (const __attribute__((address_space(1))) unsigned int*)g,
      (__attribute__((address_space(3))) unsigned int*)l, 16, 0, 0);
}

#define PJ_N 13824   // [q 0:1536][k0][k1][v0 4608:][v1 7680:][gate 10752:]
#define NTOK 2048    // B*T rows

// ---------------------------------------------------------------------------
// fp32 -> bf16 bulk convert (for x). n multiple of 8.
__global__ __launch_bounds__(256) void cvt_bf16(
    const float* __restrict__ src, short* __restrict__ dst, int n)
{
  int i = (blockIdx.x * 256 + threadIdx.x) * 8;
  if (i + 8 <= n) {
    float4 a = *(const float4*)(src + i);
    float4 b = *(const float4*)(src + i + 4);
    short v[8] = {f2bf(a.x), f2bf(a.y), f2bf(a.z), f2bf(a.w),
                  f2bf(b.x), f2bf(b.y), f2bf(b.z), f2bf(b.w)};
    uint4 u; __builtin_memcpy(&u, v, 16);
    *(uint4*)(dst + i) = u;
  }
}

// ---------------------------------------------------------------------------
// Weight transpose + convert: W (K x N, fp32) -> WT (N x K, bf16).
// R17: LDS-tiled 64x64. grid (N/64, K/64), 256 thr. Coalesced reads (lane =
// n, 256B/row) and full-line writes (4 lanes x 16B = 64B contiguous per row).
__global__ __launch_bounds__(256) void transpose_w(
    const float* __restrict__ W, short* __restrict__ WT, int K, int N)
{
  __shared__ short tile[64][68];   // +4 pad: k-stride 136B = 2-way (free)
  const int n0 = blockIdx.x * 64, k0 = blockIdx.y * 64;
  const int lane = threadIdx.x & 63, wv = threadIdx.x >> 6;
  #pragma unroll
  for (int j = 0; j < 16; ++j) {
    int kk = wv * 16 + j;
    tile[kk][lane] = f2bf(W[(size_t)(k0 + kk) * N + n0 + lane]);
  }
  __syncthreads();
  const int nr = threadIdx.x >> 2, seg = (threadIdx.x & 3) * 16;
  short v[16];
  #pragma unroll
  for (int j = 0; j < 16; ++j) v[j] = tile[seg + j][nr];
  uint4 a, b; __builtin_memcpy(&a, v, 16); __builtin_memcpy(&b, v + 8, 16);
  short* dst = WT + (size_t)(n0 + nr) * K + k0 + seg;
  *(uint4*)dst = a;
  *(uint4*)(dst + 8) = b;
}

// ---------------------------------------------------------------------------
// GEMM: C[M,N] = A[M,K] @ B, given BT (N x K). bf16 in, fp32 accum.
// 1-D grid, XCD-aware. global_load_lds staging, XOR-swizzled LDS.
template<bool F32OUT>
__global__ __launch_bounds__(256) void gemm_bt(
    const short* __restrict__ A, const short* __restrict__ BT,
    void* __restrict__ Cp, int M, int N, int K)
{
  __shared__ short As[128 * 64];
  __shared__ short Bs[128 * 64];
  const int tid = threadIdx.x;
  const int lane = tid & 63, wv = tid >> 6;
  const int quad = lane >> 4, l16 = lane & 15;
  const int j = blockIdx.x;
  const int xcd = j & 7, local = j >> 3;
  const int mtile = local & 15, ng = local >> 4;
  const int ntile = ng * 8 + xcd;
  if (ntile * 128 >= N) return;     // pad blocks no-op (uniform per block)
  const int m0 = mtile * 128, n0 = ntile * 128;
  const int wm = (wv >> 1) * 64, wn = (wv & 1) * 64;
  const int lrow = lane >> 3;              // 0..7 within staging call
  const int lperm = (lane & 7) ^ lrow;     // xor swizzle source segment
  const int xr = l16 & 7;                  // read-side xor key
  f32x4 zz = {0.f, 0.f, 0.f, 0.f};
  f32x4 acc[4][4];
  #pragma unroll
  for (int i = 0; i < 4; ++i)
    #pragma unroll
    for (int jj = 0; jj < 4; ++jj) acc[i][jj] = zz;

  for (int k0 = 0; k0 < K; k0 += 64) {
    __syncthreads();
    #pragma unroll
    for (int c = 0; c < 4; ++c) {
      int row = (wv * 4 + c) * 8 + lrow;
      gl_lds16(A  + (size_t)(m0 + row) * K + k0 + lperm * 8,
               As + (wv * 4 + c) * 512);
      gl_lds16(BT + (size_t)(n0 + row) * K + k0 + lperm * 8,
               Bs + (wv * 4 + c) * 512);
    }
    __syncthreads();
    #pragma unroll
    for (int kk = 0; kk < 64; kk += 32) {
      const int ksb = kk >> 3;
      bf16x8 af[4], bfr[4];
      #pragma unroll
      for (int i = 0; i < 4; ++i)
        af[i] = *(const bf16x8*)(As + (wm + i * 16 + l16) * 64 +
                                 (((ksb + quad) ^ xr) << 3));
      #pragma unroll
      for (int jj = 0; jj < 4; ++jj)
        bfr[jj] = *(const bf16x8*)(Bs + (wn + jj * 16 + l16) * 64 +
                                   (((ksb + quad) ^ xr) << 3));
      #pragma unroll
      for (int i = 0; i < 4; ++i)
        #pragma unroll
        for (int jj = 0; jj < 4; ++jj)
          acc[i][jj] = MFMA(af[i], bfr[jj], acc[i][jj]);
    }
  }
  #pragma unroll
  for (int i = 0; i < 4; ++i)
    #pragma unroll
    for (int jj = 0; jj < 4; ++jj)
      #pragma unroll
      for (int r = 0; r < 4; ++r) {
        int row = m0 + wm + i * 16 + quad * 4 + r;
        int col = n0 + wn + jj * 16 + l16;
        if (F32OUT) ((float*)Cp)[(size_t)row * N + col] = acc[i][jj][r];
        else        ((short*)Cp)[(size_t)row * N + col] = f2bf(acc[i][jj][r]);
      }
}

// ---------------------------------------------------------------------------
// beta (sigmoid(x@b_ws[i])) and g (-exp(A_log)*softplus(x@a_w+dt_bias)).
__global__ __launch_bounds__(64) void proj_small(
    const float* __restrict__ x, const float* __restrict__ b_ws,
    const float* __restrict__ a_w, const float* __restrict__ A_log,
    const float* __restrict__ dt_bias,
    float* __restrict__ Beta0, float* __restrict__ Beta1, float* __restrict__ G)
{
  int row = blockIdx.x, lane = threadIdx.x;
  float p[18];
  #pragma unroll
  for (int j = 0; j < 18; ++j) p[j] = 0.f;
  for (int k = lane; k < 2048; k += 64) {
    float xv = x[(size_t)row * 2048 + k];
    const float* b0 = b_ws + (size_t)k * 6;
    const float* b1 = b_ws + (size_t)2048 * 6 + (size_t)k * 6;
    const float* aw = a_w + (size_t)k * 6;
    #pragma unroll
    for (int j = 0; j < 6; ++j) {
      p[j]      += xv * b0[j];
      p[6 + j]  += xv * b1[j];
      p[12 + j] += xv * aw[j];
    }
  }
  #pragma unroll
  for (int j = 0; j < 18; ++j) {
    #pragma unroll
    for (int off = 32; off > 0; off >>= 1)
      p[j] += __shfl_down(p[j], off);
  }
  if (lane == 0) {
    #pragma unroll
    for (int j = 0; j < 6; ++j) {
      Beta0[(size_t)row * 6 + j] = 1.f / (1.f + expf(-p[j]));
      Beta1[(size_t)row * 6 + j] = 1.f / (1.f + expf(-p[6 + j]));
      float z = p[12 + j] + dt_bias[j];
      float sp = (z > 15.f) ? z : log1pf(expf(z));
      G[(size_t)row * 6 + j] = -expf(A_log[j]) * sp;
    }
  }
}

// ---------------------------------------------------------------------------
// Conv(K=4 causal, depthwise) + SiLU + per-head l2norm (q/k). grid (2048, 6).
__global__ __launch_bounds__(256) void conv_norm_qk(
    const short* __restrict__ P, const float* __restrict__ convw,
    short* __restrict__ dst, int colofs, float scale)
{
  __shared__ float red[256];
  int c = threadIdx.x, h = blockIdx.y, row = blockIdx.x;
  int t = row & 1023;
  int ch = colofs + h * 256 + c;
  const float* cw = convw + (size_t)(h * 256 + c) * 4;
  float acc = 0.f;
  #pragma unroll
  for (int j = 0; j < 4; ++j) {
    int tt = t - 3 + j;
    if (tt >= 0) acc += bf2f(P[(size_t)(row - 3 + j) * PJ_N + ch]) * cw[j];
  }
  float y = acc / (1.f + expf(-acc));   // silu
  red[c] = y * y;
  __syncthreads();
  for (int s = 128; s > 0; s >>= 1) {
    if (c < s) red[c] += red[c + s];
    __syncthreads();
  }
  float nrm = rsqrtf(red[0] + 1e-12f) * scale;
  dst[((size_t)row * 6 + h) * 256 + c] = f2bf(y * nrm);
}

// Conv + SiLU for v. grid (2048, 12).
__global__ __launch_bounds__(256) void conv_v(
    const short* __restrict__ P, const float* __restrict__ convw,
    short* __restrict__ dst, int colofs)
{
  int cg = blockIdx.y * 256 + threadIdx.x;
  int row = blockIdx.x;
  int t = row & 1023;
  const float* cw = convw + (size_t)cg * 4;
  float acc = 0.f;
  #pragma unroll
  for (int j = 0; j < 4; ++j) {
    int tt = t - 3 + j;
    if (tt >= 0) acc += bf2f(P[(size_t)(row - 3 + j) * PJ_N + colofs + cg]) * cw[j];
  }
  float y = acc / (1.f + expf(-acc));
  dst[(size_t)row * 3072 + cg] = f2bf(y);
}

// ---------------------------------------------------------------------------
// Per-(b,h,chunk) precompute of WY operands. grid (32, 6, 2), block 256.
// Qg/Mm store only odd interleaved rows (32 per chunk).
// TBV stored TRANSPOSED: [v_full=512][t=64] (R11, for b64 loads in scan).
#define KBLD 264
#define R2LD 72
#define WTLD 72
__global__ __launch_bounds__(256) void precompute_chunk(
    const short* __restrict__ Qc, const short* __restrict__ K0c, const short* __restrict__ K1c,
    const short* __restrict__ V0c, const short* __restrict__ V1c,
    const float* __restrict__ Beta0, const float* __restrict__ Beta1, const float* __restrict__ G,
    short* __restrict__ NTW, short* __restrict__ Qg, short* __restrict__ KdT,
    short* __restrict__ Mm, short* __restrict__ TBV, float* __restrict__ dC)
{
  __shared__ short r0[256 * 72];   // kb (64 x KBLD) -> wt (256 x WTLD) -> BVT
  __shared__ float Xs[64 * 64];    // A matrix (f32), consumed by substitution
  __shared__ short r2[64 * 72];    // KK^T (bf16) -> X (bf16)
  const int tid = threadIdx.x;
  const int lane = tid & 63, wv = tid >> 6;
  const int quad = lane >> 4, l16 = lane & 15;
  const int c = blockIdx.x, h = blockIdx.y, b = blockIdx.z;
  const int i0 = c * 32;
  const size_t idx = (size_t)((b * 6 + h) * 32 + c);
  short* kb = r0;
  f32x4 zz = {0.f, 0.f, 0.f, 0.f};
  bf16x8 z8 = {0, 0, 0, 0, 0, 0, 0, 0};

  // per-lane g/beta for interleaved position t = lane; wave-prefix cumsum
  float gv, betaL;
  {
    int t = lane, par = t & 1, i = i0 + (t >> 1);
    size_t gofs = (size_t)(b * 1024 + i) * 6 + h;
    gv = par ? 0.f : G[gofs];
    betaL = par ? Beta1[gofs] : Beta0[gofs];
  }
  float cum = gv;
  #pragma unroll
  for (int off = 1; off < 64; off <<= 1) {
    float nb = __shfl_up(cum, off);
    if (lane >= off) cum += nb;
  }
  float c63 = __shfl(cum, 63);
  float eBt = expf(cum);          // exp(B_t)
  float eRem = expf(c63 - cum);   // exp(B63 - B_t)
  float wsc = betaL * eBt;        // beta_t exp(B_t)
  if (tid == 0) dC[idx] = expf(c63);

  // stage k chunk (interleaved parities) into kb
  {
    int row = tid >> 2, seg = (tid & 3) * 64;
    int par = row & 1, i = i0 + (row >> 1);
    const short* src = (par ? K1c : K0c) + ((size_t)(b * 1024 + i) * 6 + h) * 256 + seg;
    short* dp = kb + row * KBLD + seg;
    #pragma unroll
    for (int e = 0; e < 64; e += 8)
      *(uint4*)(dp + e) = *(const uint4*)(src + e);
  }
  __syncthreads();

  // KK^T (bf16 into r2). wave = t row-tile.
  {
    f32x4 acc[4];
    #pragma unroll
    for (int ts = 0; ts < 4; ++ts) acc[ts] = zz;
    #pragma unroll
    for (int ks = 0; ks < 8; ++ks) {
      bf16x8 af = *(const bf16x8*)(kb + (wv * 16 + l16) * KBLD + ks * 32 + quad * 8);
      #pragma unroll
      for (int ts = 0; ts < 4; ++ts) {
        bf16x8 bfv = *(const bf16x8*)(kb + (ts * 16 + l16) * KBLD + ks * 32 + quad * 8);
        acc[ts] = MFMA(af, bfv, acc[ts]);
      }
    }
    #pragma unroll
    for (int ts = 0; ts < 4; ++ts)
      #pragma unroll
      for (int r = 0; r < 4; ++r)
        r2[(wv * 16 + quad * 4 + r) * R2LD + ts * 16 + l16] = f2bf(acc[ts][r]);
  }
  // QK^T -> M (masked, decayed; odd rows only) directly to global
  {
    f32x4 acc[4];
    #pragma unroll
    for (int ts = 0; ts < 4; ++ts) acc[ts] = zz;
    int t_row = wv * 16 + l16;
    int podd = t_row & 1, iq = i0 + (t_row >> 1);
    const short* qrow = Qc + ((size_t)(b * 1024 + iq) * 6 + h) * 256;
    #pragma unroll
    for (int ks = 0; ks < 8; ++ks) {
      bf16x8 af = z8;
      if (podd) af = *(const bf16x8*)(qrow + ks * 32 + quad * 8);
      #pragma unroll
      for (int ts = 0; ts < 4; ++ts) {
        bf16x8 bfv = *(const bf16x8*)(kb + (ts * 16 + l16) * KBLD + ks * 32 + quad * 8);
        acc[ts] = MFMA(af, bfv, acc[ts]);
      }
    }
    short* Mp = Mm + idx * 2048;
    #pragma unroll
    for (int ts = 0; ts < 4; ++ts)
      #pragma unroll
      for (int r = 1; r < 4; r += 2) {       // odd rows only
        int t = wv * 16 + quad * 4 + r, s = ts * 16 + l16;
        float ct = __shfl(cum, t), cs = __shfl(cum, s);
        float v = (s <= t) ? acc[ts][r] * expf(ct - cs) : 0.f;
        Mp[(t >> 1) * 64 + s] = f2bf(v);
      }
  }
  // Qg (odd rows only): Qg[th][d] = exp(B_{2th+1}) q_{2th+1}[d]
  {
    int th = tid >> 3, dseg = (tid & 7) * 32;
    int t = th * 2 + 1;
    float sc = __shfl(eBt, t);
    const short* qrow = Qc + ((size_t)(b * 1024 + i0 + th) * 6 + h) * 256 + dseg;
    short* qgp = Qg + idx * 8192 + (size_t)th * 256 + dseg;
    #pragma unroll
    for (int e = 0; e < 32; e += 8) {
      bf16x8 v = *(const bf16x8*)(qrow + e);
      bf16x8 w;
      #pragma unroll
      for (int q2 = 0; q2 < 8; ++q2) w[q2] = f2bf(bf2f(v[q2]) * sc);
      *(bf16x8*)(qgp + e) = w;
    }
  }
  // KdT[d][t] = exp(B63-B_t) k_t[d]
  {
    int d = tid;
    short buf[64];
    #pragma unroll
    for (int t = 0; t < 64; ++t) {
      float sc = __shfl(eRem, t);
      buf[t] = f2bf(bf2f(kb[t * KBLD + d]) * sc);
    }
    short* kp = KdT + idx * 16384 + (size_t)d * 64;
    #pragma unroll
    for (int e = 0; e < 64; e += 8) {
      uint4 v; __builtin_memcpy(&v, buf + e, 16);
      *(uint4*)(kp + e) = v;
    }
  }
  __syncthreads();

  // C1: cache kb column d = tid in registers
  short colv[64];
  {
    int d = tid;
    #pragma unroll
    for (int t = 0; t < 64; ++t) colv[t] = kb[t * KBLD + d];
  }
  // A precompute (parallel, all 256 threads): Xs[t][s] = beta_t exp(ct-cs)
  // KKT[t][s] for s<t else 0. Per iteration t is wave-uniform; s == lane, so
  // cs needs no shuffle at all.
  #pragma unroll
  for (int k = 0; k < 16; ++k) {
    int t = wv + k * 4;
    float bt = __shfl(betaL, t);
    float ct = __shfl(cum, t);
    float a = (lane < t) ? bt * expf(ct - cum) * bf2f(r2[t * R2LD + lane]) : 0.f;
    Xs[t * 64 + lane] = a;
  }
  __syncthreads();
  // C2: wt[d][s] = beta_s exp(B_s) k_s[d] (over r0)
  {
    int d = tid;
    short wrow[64];
    #pragma unroll
    for (int s = 0; s < 64; ++s) wrow[s] = f2bf(bf2f(colv[s]) * __shfl(wsc, s));
    short* wp = r0 + d * WTLD;
    #pragma unroll
    for (int e = 0; e < 64; e += 8) {
      uint4 v; __builtin_memcpy(&v, wrow + e, 16);
      *(uint4*)(wp + e) = v;
    }
  }
  // C3: wave0 solves X = (I+A)^-1 by forward substitution, column j = lane,
  // X entirely in registers (static triangular unroll; A read as broadcast
  // float2 from LDS). Writes bf16 X directly into r2.
  if (wv == 0) {
    const int j = lane;
    float xcol[64];
    #pragma unroll
    for (int t = 0; t < 64; ++t) {
      float sa0 = 0.f, sa1 = 0.f;
      const float2* ap = (const float2*)(Xs + t * 64);
      #pragma unroll
      for (int s = 0; s + 1 < t; s += 2) {
        float2 av = ap[s >> 1];
        sa0 += av.x * xcol[s];
        sa1 += av.y * xcol[s + 1];
      }
      if (t & 1) sa0 += Xs[t * 64 + (t - 1)] * xcol[t - 1];
      float xv = ((t == j) ? 1.f : 0.f) - (sa0 + sa1);
      xcol[t] = xv;
      r2[t * R2LD + j] = f2bf(xv);
    }
  }
  __syncthreads();
  // NTW = -(X @ W)
  {
    f32x4 acc[4][4];
    #pragma unroll
    for (int i = 0; i < 4; ++i)
      #pragma unroll
      for (int j = 0; j < 4; ++j) acc[i][j] = zz;
    #pragma unroll
    for (int ks = 0; ks < 2; ++ks) {
      bf16x8 af[4], bfv[4];
      #pragma unroll
      for (int tt = 0; tt < 4; ++tt)
        af[tt] = *(const bf16x8*)(r2 + (tt * 16 + l16) * R2LD + ks * 32 + quad * 8);
      #pragma unroll
      for (int dt = 0; dt < 4; ++dt)
        bfv[dt] = *(const bf16x8*)(r0 + ((wv * 4 + dt) * 16 + l16) * WTLD + ks * 32 + quad * 8);
      #pragma unroll
      for (int tt = 0; tt < 4; ++tt)
        #pragma unroll
        for (int dt = 0; dt < 4; ++dt)
          acc[tt][dt] = MFMA(af[tt], bfv[dt], acc[tt][dt]);
    }
    short* np = NTW + idx * 16384;
    #pragma unroll
    for (int tt = 0; tt < 4; ++tt)
      #pragma unroll
      for (int dt = 0; dt < 4; ++dt)
        #pragma unroll
        for (int r = 0; r < 4; ++r) {
          int t = tt * 16 + quad * 4 + r, d = (wv * 4 + dt) * 16 + l16;
          np[t * 256 + d] = f2bf(-acc[tt][dt][r]);
        }
  }
  __syncthreads();
  // TBV = X @ (beta*v), two DV halves through r0; stored [v_full][t] (b64)
  for (int vh = 0; vh < 2; ++vh) {
    {
      int vl = tid;
      short bv[64];
      #pragma unroll
      for (int t = 0; t < 64; ++t) {
        int par = t & 1, i = i0 + (t >> 1);
        const short* src = (par ? V1c : V0c) + (size_t)(b * 1024 + i) * 3072 + h * 512 + vh * 256 + vl;
        bv[t] = f2bf(bf2f(*src) * __shfl(betaL, t));
      }
      short* bp = r0 + vl * WTLD;
      #pragma unroll
      for (int e = 0; e < 64; e += 8) {
        uint4 v; __builtin_memcpy(&v, bv + e, 16);
        *(uint4*)(bp + e) = v;
      }
    }
    __syncthreads();
    {
      f32x4 acc[4][4];
      #pragma unroll
      for (int i = 0; i < 4; ++i)
        #pragma unroll
        for (int j = 0; j < 4; ++j) acc[i][j] = zz;
      #pragma unroll
      for (int ks = 0; ks < 2; ++ks) {
        bf16x8 af[4], bfv[4];
        #pragma unroll
        for (int tt = 0; tt < 4; ++tt)
          af[tt] = *(const bf16x8*)(r2 + (tt * 16 + l16) * R2LD + ks * 32 + quad * 8);
        #pragma unroll
        for (int vt = 0; vt < 4; ++vt)
          bfv[vt] = *(const bf16x8*)(r0 + ((wv * 4 + vt) * 16 + l16) * WTLD + ks * 32 + quad * 8);
        #pragma unroll
        for (int tt = 0; tt < 4; ++tt)
          #pragma unroll
          for (int vt = 0; vt < 4; ++vt)
            acc[tt][vt] = MFMA(af[tt], bfv[vt], acc[tt][vt]);
      }
      short* tp = TBV + idx * 32768;
      #pragma unroll
      for (int tt = 0; tt < 4; ++tt)
        #pragma unroll
        for (int vt = 0; vt < 4; ++vt) {
          // D frag: row = t = tt*16+quad*4+r, col = v = (wv*4+vt)*16+l16
          int vfull = vh * 256 + (wv * 4 + vt) * 16 + l16;
          int t0 = tt * 16 + quad * 4;
          short w[4];
          #pragma unroll
          for (int r = 0; r < 4; ++r) w[r] = f2bf(acc[tt][vt][r]);
          uint2 uv; __builtin_memcpy(&uv, w, 8);
          *(uint2*)(tp + (size_t)vfull * 64 + t0) = uv;
        }
    }
    __syncthreads();
  }
}

// ---------------------------------------------------------------------------
// Scan: 2-wave blocks (128 thr) per (b,h,16-col DV slice). grid 384.
// R16: cross-chunk pipeline. R17: phase1/oac accumulator chains split 2-way.
#define SLD 264
#define ULD 72
__global__ __launch_bounds__(128) void scan_kernel(
    const short* __restrict__ NTW, const short* __restrict__ Qg,
    const short* __restrict__ KdT, const short* __restrict__ Mm,
    const short* __restrict__ TBV, const float* __restrict__ dC,
    short* __restrict__ O)
{
  __shared__ short NTWs[2][64 * 256]; // 64KB dbuf, LDS[t][s]=G[t][s^(t&7)]
  __shared__ short S[16 * SLD];       // state slice [v_local][d], bf16
  __shared__ short U[16 * ULD];       // u slice [v_local][t], bf16
  const int tid = threadIdx.x;
  const int lane = tid & 63, w = tid >> 6;
  const int quad = lane >> 4, l16 = lane & 15;
  const int xk = l16 & 7;           // read-side xor key
  const int r2l = lane >> 5;        // staging: row within pair
  const int s32 = lane & 31;        // staging: 16B seg 0..31
  // XCD-aware swizzle (bijective, 384 = 8 xcd * 48)
  const int gid = (blockIdx.x & 7) * 48 + (blockIdx.x >> 3);
  const int bh = gid >> 5, slice = gid & 31;
  const int b = bh / 6, h = bh % 6;
  const int vbase = slice * 16;
  f32x4 zz = {0.f, 0.f, 0.f, 0.f};
  for (int e = tid; e < 16 * SLD; e += 128) S[e] = 0;

  // prologue: stage chunk 0 NTW (own rows) into buf0, full drain
  {
    const short* ntw0 = NTW + (size_t)(bh * 32) * 16384;
    #pragma unroll
    for (int j = 0; j < 16; ++j) {
      int row = 32 * w + 2 * j + r2l;
      gl_lds16(ntw0 + (size_t)row * 256 + ((s32 ^ (row & 7)) << 3),
               &NTWs[0][(32 * w + 2 * j) * 256]);
    }
  }
  __syncthreads();   // drains vmcnt+lgkm: staging-0 + S init visible

  for (int c = 0; c < 32; ++c) {
    size_t idx = (size_t)(bh * 32 + c);
    const short* qg  = Qg  + idx * 8192;
    const short* kdt = KdT + idx * 16384;
    const short* mp  = Mm  + idx * 2048;
    const short* tb  = TBV + idx * 32768;
    short* bufC = &NTWs[c & 1][0];
    short* bufN = &NTWs[(c & 1) ^ 1][0];
    const int cn = (c + 1) & 31;   // wrap: uniform counts, never consumed stale
    const short* ntwN = NTW + (size_t)(bh * 32 + cn) * 16384;

    // top wait: staging for THIS chunk landed (<=4 older O-stores remain)
    asm volatile("s_waitcnt vmcnt(4)" ::: "memory");
    __builtin_amdgcn_sched_barrier(0);

    // reg loads for c: dc, Qg(8), Mm(2), TBV(2), KdT(16)
    float dc = dC[idx];
    bf16x8 qgr[8];
    #pragma unroll
    for (int ks = 0; ks < 8; ++ks)
      qgr[ks] = *(const bf16x8*)(
          qg + (size_t)(w * 16 + l16) * 256 + ks * 32 + quad * 8);
    bf16x8 mmr2[2];
    #pragma unroll
    for (int ks = 0; ks < 2; ++ks)
      mmr2[ks] = *(const bf16x8*)(mp + (w * 16 + l16) * 64 + ks * 32 + quad * 8);
    bf16x4 tbv2[2];
    #pragma unroll
    for (int j = 0; j < 2; ++j)
      tbv2[j] = *(const bf16x4*)(
          tb + (size_t)(vbase + l16) * 64 + (2 * w + j) * 16 + quad * 4);
    bf16x8 kdr2[2][2][4];
    #pragma unroll
    for (int j = 0; j < 2; ++j)
      #pragma unroll
      for (int ks = 0; ks < 2; ++ks)
        #pragma unroll
        for (int dt = 0; dt < 4; ++dt)
          kdr2[j][ks][dt] = *(const bf16x8*)(
              kdt + (size_t)(((2 * w + j) * 4 + dt) * 16 + l16) * 64 + ks * 32 + quad * 8);
    __builtin_amdgcn_sched_barrier(0);

    // issue staging for NEXT chunk into bufN (own rows, 16 gl_lds)
    #pragma unroll
    for (int j = 0; j < 16; ++j) {
      int row = 32 * w + 2 * j + r2l;
      gl_lds16(ntwN + (size_t)row * 256 + ((s32 ^ (row & 7)) << 3),
               bufN + (32 * w + 2 * j) * 256);
    }
    __builtin_amdgcn_sched_barrier(0);

    // --- phase 1: uac = NTW@S0 (own 2 tiles), 2-way chain split (R17) ---
    f32x4 uA0 = zz, uB0 = zz, uA1 = zz, uB1 = zz;
    __builtin_amdgcn_s_setprio(1);
    #pragma unroll
    for (int ks = 0; ks < 4; ++ks) {
      bf16x8 bfv0 = *(const bf16x8*)(S + l16 * SLD + ks * 32 + quad * 8);
      bf16x8 bfv1 = *(const bf16x8*)(S + l16 * SLD + (ks + 4) * 32 + quad * 8);
      int gx0 = ks * 4 + quad, gx1 = (ks + 4) * 4 + quad;
      bf16x8 a00 = *(const bf16x8*)(bufC + ((2 * w + 0) * 16 + l16) * 256 + ((gx0 ^ xk) << 3));
      bf16x8 a01 = *(const bf16x8*)(bufC + ((2 * w + 0) * 16 + l16) * 256 + ((gx1 ^ xk) << 3));
      bf16x8 a10 = *(const bf16x8*)(bufC + ((2 * w + 1) * 16 + l16) * 256 + ((gx0 ^ xk) << 3));
      bf16x8 a11 = *(const bf16x8*)(bufC + ((2 * w + 1) * 16 + l16) * 256 + ((gx1 ^ xk) << 3));
      uA0 = MFMA(a00, bfv0, uA0);
      uB0 = MFMA(a01, bfv1, uB0);
      uA1 = MFMA(a10, bfv0, uA1);
      uB1 = MFMA(a11, bfv1, uB1);
    }
    __builtin_amdgcn_s_setprio(0);
    f32x4 uac2[2];
    #pragma unroll
    for (int r = 0; r < 4; ++r) { uac2[0][r] = uA0[r] + uB0[r]; uac2[1][r] = uA1[r] + uB1[r]; }

    // dc/Qg/Mm/TBV done (KdT 16 + staging 16 may remain in flight)
    asm volatile("s_waitcnt vmcnt(32)" ::: "memory");
    __builtin_amdgcn_sched_barrier(0);

    // --- u = uac + TBV -> U (own tiles, b64 writes) ---
    #pragma unroll
    for (int j = 0; j < 2; ++j) {
      short wb[4];
      #pragma unroll
      for (int r = 0; r < 4; ++r) wb[r] = f2bf(uac2[j][r] + bf2f(tbv2[j][r]));
      uint2 uv; __builtin_memcpy(&uv, wb, 8);
      *(uint2*)(U + l16 * ULD + (2 * w + j) * 16 + quad * 4) = uv;
    }
    // bar1: U complete, phase1 S reads retired
    asm volatile("s_waitcnt lgkmcnt(0)" ::: "memory");
    __builtin_amdgcn_s_barrier();
    __builtin_amdgcn_sched_barrier(0);

    // --- oac = Qg @ S0 + M @ u (own tile), 2-way chain split (R17) ---
    f32x4 oA = zz, oB = zz;
    #pragma unroll
    for (int ks = 0; ks < 4; ++ks) {
      bf16x8 bfv0 = *(const bf16x8*)(S + l16 * SLD + ks * 32 + quad * 8);
      bf16x8 bfv1 = *(const bf16x8*)(S + l16 * SLD + (ks + 4) * 32 + quad * 8);
      oA = MFMA(qgr[ks], bfv0, oA);
      oB = MFMA(qgr[ks + 4], bfv1, oB);
    }
    {
      bf16x8 ub0 = *(const bf16x8*)(U + l16 * ULD + 0 * 32 + quad * 8);
      bf16x8 ub1 = *(const bf16x8*)(U + l16 * ULD + 1 * 32 + quad * 8);
      oA = MFMA(mmr2[0], ub0, oA);
      oB = MFMA(mmr2[1], ub1, oB);
    }
    f32x4 oac;
    #pragma unroll
    for (int r = 0; r < 4; ++r) oac[r] = oA[r] + oB[r];

    // --- O store (4 stores; may stay in flight across chunk boundary) ---
    #pragma unroll
    for (int r = 0; r < 4; ++r) {
      int th = w * 16 + quad * 4 + r;
      int i = c * 32 + th;
      O[((size_t)(b * 1024 + i) * 6 + h) * 512 + vbase + l16] = f2bf(oac[r]);
    }

    // KdT done (staging 16 + stores 4 may remain)
    asm volatile("s_waitcnt vmcnt(20)" ::: "memory");
    __builtin_amdgcn_sched_barrier(0);

    // bar2: both waves' oac S0-reads retired before S-phase overwrites S
    asm volatile("s_waitcnt lgkmcnt(0)" ::: "memory");
    __builtin_amdgcn_s_barrier();
    __builtin_amdgcn_sched_barrier(0);

    // --- S1 = dc * S0 + KdT @ u (own g2 halves, b64 S reads/writes) ---
    __builtin_amdgcn_s_setprio(1);
    #pragma unroll
    for (int j = 0; j < 2; ++j) {
      const int g2 = 2 * w + j;
      f32x4 sac[4];
      #pragma unroll
      for (int dt = 0; dt < 4; ++dt) {
        bf16x4 sv = *(const bf16x4*)(S + l16 * SLD + (g2 * 4 + dt) * 16 + quad * 4);
        #pragma unroll
        for (int r = 0; r < 4; ++r) sac[dt][r] = dc * bf2f(sv[r]);
      }
      #pragma unroll
      for (int ks = 0; ks < 2; ++ks) {
        bf16x8 bfv = *(const bf16x8*)(U + l16 * ULD + ks * 32 + quad * 8);
        #pragma unroll
        for (int dt = 0; dt < 4; ++dt)
          sac[dt] = MFMA(kdr2[j][ks][dt], bfv, sac[dt]);
      }
      #pragma unroll
      for (int dt = 0; dt < 4; ++dt) {
        short wb[4];
        #pragma unroll
        for (int r = 0; r < 4; ++r) wb[r] = f2bf(sac[dt][r]);
        uint2 uv; __builtin_memcpy(&uv, wb, 8);
        *(uint2*)(S + l16 * SLD + (g2 * 4 + dt) * 16 + quad * 4) = uv;
      }
    }
    __builtin_amdgcn_s_setprio(0);
    // bar3: S complete for next chunk's phase1/oac
    asm volatile("s_waitcnt lgkmcnt(0)" ::: "memory");
    __builtin_amdgcn_s_barrier();
    __builtin_amdgcn_sched_barrier(0);
  }
}

// ---------------------------------------------------------------------------
// RMS-norm over DV per (b,t,h), times silu(gate). grid (2048, 6).
__global__ __launch_bounds__(256) void rms_gate(
    const short* __restrict__ O, const short* __restrict__ P,
    const float* __restrict__ onw, short* __restrict__ OutPre)
{
  __shared__ float red[256];
  int tid = threadIdx.x, h = blockIdx.y, row = blockIdx.x;
  size_t base = ((size_t)row * 6 + h) * 512;
  float a = bf2f(O[base + tid]), b2 = bf2f(O[base + 256 + tid]);
  red[tid] = a * a + b2 * b2;
  __syncthreads();
  for (int s = 128; s > 0; s >>= 1) {
    if (tid < s) red[tid] += red[tid + s];
    __syncthreads();
  }
  float r = rsqrtf(red[0] * (1.f / 512.f) + 1e-5f);
  #pragma unroll
  for (int half = 0; half < 2; ++half) {
    int col = tid + half * 256;
    float ov = half ? b2 : a;
    float g = bf2f(P[(size_t)row * PJ_N + 10752 + h * 512 + col]);
    float sg = g / (1.f + expf(-g));
    OutPre[(size_t)row * 3072 + h * 512 + col] = f2bf(ov * r * onw[col] * sg);
  }
}

// ---------------------------------------------------------------------------
extern "C" void kernel_launch(void* const* d_in, const int* in_sizes, int n_in,
                              void* d_out, int out_size, void* d_ws, size_t ws_size,
                              hipStream_t stream) {
  const float* x        = (const float*)d_in[0];
  const float* q_w      = (const float*)d_in[1];
  const float* k_ws     = (const float*)d_in[2];
  const float* v_ws     = (const float*)d_in[3];
  const float* b_ws     = (const float*)d_in[4];
  const float* a_w      = (const float*)d_in[5];
  const float* g_w      = (const float*)d_in[6];
  const float* o_w      = (const float*)d_in[7];
  const float* q_conv_w = (const float*)d_in[8];
  const float* k_conv   = (const float*)d_in[9];
  const float* v_conv   = (const float*)d_in[10];
  const float* A_log    = (const float*)d_in[11];
  const float* dt_bias  = (const float*)d_in[12];
  const float* o_norm_w = (const float*)d_in[13];
  float* out = (float*)d_out;

  char* ws = (char*)d_ws;
  size_t off = 0;
  auto take = [&](size_t bytes) {
    size_t r = off;
    off += (bytes + 255) & ~(size_t)255;
    return r;
  };
  // Persistent buffers
  short* P  = (short*)(ws + take((size_t)NTOK * PJ_N * 2));   // live 3-8
  short* oT = (short*)(ws + take((size_t)2048 * 3072 * 2));   // live 2-9
  // xbf (step 3 only) reused for Mm (steps 6-7)
  size_t regX = take((size_t)NTOK * 2048 * 2);                // 8.39 MB
  short* xbf = (short*)(ws + regX);
  short* Mm  = (short*)(ws + regX);                           // 1.57 MB
  // Region A: WTall (steps 2-3) reused for NTW|Qg|KdT|TBV (steps 6-7)
  size_t regA = take((size_t)PJ_N * 2048 * 2);                // 56,623,104 B
  short* WTall = (short*)(ws + regA);
  short* NTW = (short*)(ws + regA);
  short* Qg  = NTW + (size_t)384 * 16384;
  short* KdT = Qg  + (size_t)384 * 8192;
  short* TBV = KdT + (size_t)384 * 16384;   // ends exactly at regA + 56,623,104
  // Region B: conv outputs (steps 5-6) reused for O/OutPre (steps 7-9)
  size_t regB = take((size_t)44040192);                       // 44.0 MB
  short* Qc  = (short*)(ws + regB);
  short* K0c = Qc  + (size_t)NTOK * 1536;
  short* K1c = K0c + (size_t)NTOK * 1536;
  short* V0c = K1c + (size_t)NTOK * 1536;
  short* V1c = V0c + (size_t)NTOK * 3072;
  short* O      = (short*)(ws + regB);                        // 12.6 MB
  short* OutPre = O + (size_t)NTOK * 6 * 512;                 // 12.6 MB
  float* Beta0 = (float*)(ws + take((size_t)NTOK * 6 * 4));
  float* Beta1 = (float*)(ws + take((size_t)NTOK * 6 * 4));
  float* G     = (float*)(ws + take((size_t)NTOK * 6 * 4));
  float* dCp   = (float*)(ws + take((size_t)384 * 4));
  if (off > ws_size) return;  // ws too small: no-op (diagnosable, capture-safe)

  // 1) convert x to bf16
  cvt_bf16<<<dim3(NTOK * 2048 / 8 / 256), 256, 0, stream>>>(x, xbf, NTOK * 2048);

  // 2) weight transposes (fp32 -> bf16), LDS-tiled (R17). grid (N/64, K/64).
  transpose_w<<<dim3(24, 32), 256, 0, stream>>>(q_w, WTall, 2048, 1536);
  transpose_w<<<dim3(24, 32), 256, 0, stream>>>(k_ws, WTall + (size_t)1536 * 2048, 2048, 1536);
  transpose_w<<<dim3(24, 32), 256, 0, stream>>>(k_ws + (size_t)2048 * 1536, WTall + (size_t)3072 * 2048, 2048, 1536);
  transpose_w<<<dim3(48, 32), 256, 0, stream>>>(v_ws, WTall + (size_t)4608 * 2048, 2048, 3072);
  transpose_w<<<dim3(48, 32), 256, 0, stream>>>(v_ws + (size_t)2048 * 3072, WTall + (size_t)7680 * 2048, 2048, 3072);
  transpose_w<<<dim3(48, 32), 256, 0, stream>>>(g_w, WTall + (size_t)10752 * 2048, 2048, 3072);
  transpose_w<<<dim3(32, 48), 256, 0, stream>>>(o_w, oT, 3072, 2048);

  // 3) fused projection GEMM (XCD-aware 1-D grid, N padded 108->112 tiles)
  gemm_bt<false><<<dim3(16 * 112), 256, 0, stream>>>(
      xbf, WTall, P, NTOK, PJ_N, 2048);

  // 4) beta / g (fp32 inputs straight from d_in)
  proj_small<<<dim3(NTOK), 64, 0, stream>>>(x, b_ws, a_w, A_log, dt_bias, Beta0, Beta1, G);

  // 5) conv + silu (+ l2norm for q/k)
  conv_norm_qk<<<dim3(NTOK, 6), 256, 0, stream>>>(P, q_conv_w, Qc, 0, 0.0625f);
  conv_norm_qk<<<dim3(NTOK, 6), 256, 0, stream>>>(P, k_conv, K0c, 1536, 1.f);
  conv_norm_qk<<<dim3(NTOK, 6), 256, 0, stream>>>(P, k_conv + (size_t)1536 * 4, K1c, 3072, 1.f);
  conv_v<<<dim3(NTOK, 12), 256, 0, stream>>>(P, v_conv, V0c, 4608);
  conv_v<<<dim3(NTOK, 12), 256, 0, stream>>>(P, v_conv + (size_t)3072 * 4, V1c, 7680);

  // 6) chunk operand precompute (WY form)
  precompute_chunk<<<dim3(32, 6, 2), 256, 0, stream>>>(Qc, K0c, K1c, V0c, V1c,
      Beta0, Beta1, G, NTW, Qg, KdT, Mm, TBV, dCp);

  // 7) sequential chunk scan (384 blocks x 2 waves, cross-chunk pipeline)
  scan_kernel<<<dim3(384), 128, 0, stream>>>(NTW, Qg, KdT, Mm, TBV, dCp, O);

  // 8) rms-norm * silu(gate)
  rms_gate<<<dim3(NTOK, 6), 256, 0, stream>>>(O, P, o_norm_w, OutPre);

  // 9) output projection (fp32 out)
  gemm_bt<true><<<dim3(16 * 16), 256, 0, stream>>>(
      OutPre, oT, out, NTOK, 2048, 3072);
}

// Round 11
// 738.027 us; speedup vs baseline: 1.5373x; 1.0907x over previous
//
#include <hip/hip_runtime.h>

// ---------------------------------------------------------------------------
// GatedDeltaProduct: B=2,T=1024,HID=2048, NH=2, H=6, DK=256, DV=512, CHUNK=64
// Inputs fp32, output fp32. Internal bf16 MFMA. WY chunked gated delta rule.
// R9:  precompute C3 register substitution (394us -> ~100us).
// R17: transpose_w LDS-tiled (uncoalesced-write fix): total 1117 -> 805us.
//      Scan ILP split neutral -> dep-chain depth not the issue.
// R18: scan operand COALESCING fix. Scan's reg loads were lane-strided
//      gathers (KdT/Qg: 16B/lane at 128-512B stride = 64 lines/instr;
//      TBV: 8B/lane at 128B stride) — same pathology as the old transpose.
//      KdT/Qg/TBV now stored by precompute in FRAGMENT ORDER
//      (block x lane x 16B) so every scan load is base + lane*16B,
//      1KB contiguous per instr. Mm kept (4KB L2-hot, 2 instrs).
//      + proj_small loads vectorized (18 scalar -> 9 float2).
// R19: identical resubmit of R18 (container failed twice = infra flake;
//      layout indexing re-audited in-bounds, kernel never measured).
// Layouts:
//   KdT[idx]: ((dblk*2+ks)*64 + lane)*8 shorts, dblk=d>>4 (=(2w+j)*4+dt)
//   Qg [idx]: ((w*8+ks)*64 + lane)*8 shorts
//   TBV[idx]: ((slice*4 + tt)*64 + lane)*4 shorts, tt=2w+j
// ---------------------------------------------------------------------------

typedef short bf16x8 __attribute__((ext_vector_type(8)));
typedef short bf16x4 __attribute__((ext_vector_type(4)));
typedef float f32x4 __attribute__((ext_vector_type(4)));

__device__ __forceinline__ float bf2f(short s) {
  unsigned u = ((unsigned)(unsigned short)s) << 16;
  float f; __builtin_memcpy(&f, &u, 4); return f;
}
__device__ __forceinline__ short f2bf(float f) {
  unsigned u; __builtin_memcpy(&u, &f, 4);
  u = (u + 0x7FFFu + ((u >> 16) & 1u)) >> 16;
  return (short)u;
}
__device__ __forceinline__ f32x4 MFMA(bf16x8 a, bf16x8 b, f32x4 c) {
  return __builtin_amdgcn_mfma_f32_16x16x32_bf16(a, b, c, 0, 0, 0);
}
// async global->LDS, 16B per lane; lds dest = wave-uniform base + lane*16
__device__ __forceinline__ void gl_lds16(const short* g, short* l) {
  __builtin_amdgcn_global_load_lds(
      (const __attribute__((address_space(1))) unsigned int*)g,
      (__attribute__((address_space(3))) unsigned int*)l, 16, 0, 0);
}

#define PJ_N 13824   // [q 0:1536][k0][k1][v0 4608:][v1 7680:][gate 10752:]
#define NTOK 2048    // B*T rows

// ---------------------------------------------------------------------------
// fp32 -> bf16 bulk convert (for x). n multiple of 8.
__global__ __launch_bounds__(256) void cvt_bf16(
    const float* __restrict__ src, short* __restrict__ dst, int n)
{
  int i = (blockIdx.x * 256 + threadIdx.x) * 8;
  if (i + 8 <= n) {
    float4 a = *(const float4*)(src + i);
    float4 b = *(const float4*)(src + i + 4);
    short v[8] = {f2bf(a.x), f2bf(a.y), f2bf(a.z), f2bf(a.w),
                  f2bf(b.x), f2bf(b.y), f2bf(b.z), f2bf(b.w)};
    uint4 u; __builtin_memcpy(&u, v, 16);
    *(uint4*)(dst + i) = u;
  }
}

// ---------------------------------------------------------------------------
// Weight transpose + convert: W (K x N, fp32) -> WT (N x K, bf16).
// LDS-tiled 64x64 (R17). grid (N/64, K/64), 256 thr.
__global__ __launch_bounds__(256) void transpose_w(
    const float* __restrict__ W, short* __restrict__ WT, int K, int N)
{
  __shared__ short tile[64][68];   // +4 pad: k-stride 136B = 2-way (free)
  const int n0 = blockIdx.x * 64, k0 = blockIdx.y * 64;
  const int lane = threadIdx.x & 63, wv = threadIdx.x >> 6;
  #pragma unroll
  for (int j = 0; j < 16; ++j) {
    int kk = wv * 16 + j;
    tile[kk][lane] = f2bf(W[(size_t)(k0 + kk) * N + n0 + lane]);
  }
  __syncthreads();
  const int nr = threadIdx.x >> 2, seg = (threadIdx.x & 3) * 16;
  short v[16];
  #pragma unroll
  for (int j = 0; j < 16; ++j) v[j] = tile[seg + j][nr];
  uint4 a, b; __builtin_memcpy(&a, v, 16); __builtin_memcpy(&b, v + 8, 16);
  short* dst = WT + (size_t)(n0 + nr) * K + k0 + seg;
  *(uint4*)dst = a;
  *(uint4*)(dst + 8) = b;
}

// ---------------------------------------------------------------------------
// GEMM: C[M,N] = A[M,K] @ B, given BT (N x K). bf16 in, fp32 accum.
// 1-D grid, XCD-aware. global_load_lds staging, XOR-swizzled LDS.
template<bool F32OUT>
__global__ __launch_bounds__(256) void gemm_bt(
    const short* __restrict__ A, const short* __restrict__ BT,
    void* __restrict__ Cp, int M, int N, int K)
{
  __shared__ short As[128 * 64];
  __shared__ short Bs[128 * 64];
  const int tid = threadIdx.x;
  const int lane = tid & 63, wv = tid >> 6;
  const int quad = lane >> 4, l16 = lane & 15;
  const int j = blockIdx.x;
  const int xcd = j & 7, local = j >> 3;
  const int mtile = local & 15, ng = local >> 4;
  const int ntile = ng * 8 + xcd;
  if (ntile * 128 >= N) return;     // pad blocks no-op (uniform per block)
  const int m0 = mtile * 128, n0 = ntile * 128;
  const int wm = (wv >> 1) * 64, wn = (wv & 1) * 64;
  const int lrow = lane >> 3;              // 0..7 within staging call
  const int lperm = (lane & 7) ^ lrow;     // xor swizzle source segment
  const int xr = l16 & 7;                  // read-side xor key
  f32x4 zz = {0.f, 0.f, 0.f, 0.f};
  f32x4 acc[4][4];
  #pragma unroll
  for (int i = 0; i < 4; ++i)
    #pragma unroll
    for (int jj = 0; jj < 4; ++jj) acc[i][jj] = zz;

  for (int k0 = 0; k0 < K; k0 += 64) {
    __syncthreads();
    #pragma unroll
    for (int c = 0; c < 4; ++c) {
      int row = (wv * 4 + c) * 8 + lrow;
      gl_lds16(A  + (size_t)(m0 + row) * K + k0 + lperm * 8,
               As + (wv * 4 + c) * 512);
      gl_lds16(BT + (size_t)(n0 + row) * K + k0 + lperm * 8,
               Bs + (wv * 4 + c) * 512);
    }
    __syncthreads();
    #pragma unroll
    for (int kk = 0; kk < 64; kk += 32) {
      const int ksb = kk >> 3;
      bf16x8 af[4], bfr[4];
      #pragma unroll
      for (int i = 0; i < 4; ++i)
        af[i] = *(const bf16x8*)(As + (wm + i * 16 + l16) * 64 +
                                 (((ksb + quad) ^ xr) << 3));
      #pragma unroll
      for (int jj = 0; jj < 4; ++jj)
        bfr[jj] = *(const bf16x8*)(Bs + (wn + jj * 16 + l16) * 64 +
                                   (((ksb + quad) ^ xr) << 3));
      #pragma unroll
      for (int i = 0; i < 4; ++i)
        #pragma unroll
        for (int jj = 0; jj < 4; ++jj)
          acc[i][jj] = MFMA(af[i], bfr[jj], acc[i][jj]);
    }
  }
  #pragma unroll
  for (int i = 0; i < 4; ++i)
    #pragma unroll
    for (int jj = 0; jj < 4; ++jj)
      #pragma unroll
      for (int r = 0; r < 4; ++r) {
        int row = m0 + wm + i * 16 + quad * 4 + r;
        int col = n0 + wn + jj * 16 + l16;
        if (F32OUT) ((float*)Cp)[(size_t)row * N + col] = acc[i][jj][r];
        else        ((short*)Cp)[(size_t)row * N + col] = f2bf(acc[i][jj][r]);
      }
}

// ---------------------------------------------------------------------------
// beta (sigmoid(x@b_ws[i])) and g (-exp(A_log)*softplus(x@a_w+dt_bias)).
// R18: float2-vectorized weight loads (was 18 scalar per k).
__global__ __launch_bounds__(64) void proj_small(
    const float* __restrict__ x, const float* __restrict__ b_ws,
    const float* __restrict__ a_w, const float* __restrict__ A_log,
    const float* __restrict__ dt_bias,
    float* __restrict__ Beta0, float* __restrict__ Beta1, float* __restrict__ G)
{
  int row = blockIdx.x, lane = threadIdx.x;
  float p[18];
  #pragma unroll
  for (int j = 0; j < 18; ++j) p[j] = 0.f;
  for (int k = lane; k < 2048; k += 64) {
    float xv = x[(size_t)row * 2048 + k];
    const float2* b0 = (const float2*)(b_ws + (size_t)k * 6);
    const float2* b1 = (const float2*)(b_ws + (size_t)2048 * 6 + (size_t)k * 6);
    const float2* aw = (const float2*)(a_w + (size_t)k * 6);
    #pragma unroll
    for (int j = 0; j < 3; ++j) {
      float2 v0 = b0[j], v1 = b1[j], v2 = aw[j];
      p[2 * j]      += xv * v0.x; p[2 * j + 1]      += xv * v0.y;
      p[6 + 2 * j]  += xv * v1.x; p[6 + 2 * j + 1]  += xv * v1.y;
      p[12 + 2 * j] += xv * v2.x; p[12 + 2 * j + 1] += xv * v2.y;
    }
  }
  #pragma unroll
  for (int j = 0; j < 18; ++j) {
    #pragma unroll
    for (int off = 32; off > 0; off >>= 1)
      p[j] += __shfl_down(p[j], off);
  }
  if (lane == 0) {
    #pragma unroll
    for (int j = 0; j < 6; ++j) {
      Beta0[(size_t)row * 6 + j] = 1.f / (1.f + expf(-p[j]));
      Beta1[(size_t)row * 6 + j] = 1.f / (1.f + expf(-p[6 + j]));
      float z = p[12 + j] + dt_bias[j];
      float sp = (z > 15.f) ? z : log1pf(expf(z));
      G[(size_t)row * 6 + j] = -expf(A_log[j]) * sp;
    }
  }
}

// ---------------------------------------------------------------------------
// Conv(K=4 causal, depthwise) + SiLU + per-head l2norm (q/k). grid (2048, 6).
__global__ __launch_bounds__(256) void conv_norm_qk(
    const short* __restrict__ P, const float* __restrict__ convw,
    short* __restrict__ dst, int colofs, float scale)
{
  __shared__ float red[256];
  int c = threadIdx.x, h = blockIdx.y, row = blockIdx.x;
  int t = row & 1023;
  int ch = colofs + h * 256 + c;
  const float* cw = convw + (size_t)(h * 256 + c) * 4;
  float acc = 0.f;
  #pragma unroll
  for (int j = 0; j < 4; ++j) {
    int tt = t - 3 + j;
    if (tt >= 0) acc += bf2f(P[(size_t)(row - 3 + j) * PJ_N + ch]) * cw[j];
  }
  float y = acc / (1.f + expf(-acc));   // silu
  red[c] = y * y;
  __syncthreads();
  for (int s = 128; s > 0; s >>= 1) {
    if (c < s) red[c] += red[c + s];
    __syncthreads();
  }
  float nrm = rsqrtf(red[0] + 1e-12f) * scale;
  dst[((size_t)row * 6 + h) * 256 + c] = f2bf(y * nrm);
}

// Conv + SiLU for v. grid (2048, 12).
__global__ __launch_bounds__(256) void conv_v(
    const short* __restrict__ P, const float* __restrict__ convw,
    short* __restrict__ dst, int colofs)
{
  int cg = blockIdx.y * 256 + threadIdx.x;
  int row = blockIdx.x;
  int t = row & 1023;
  const float* cw = convw + (size_t)cg * 4;
  float acc = 0.f;
  #pragma unroll
  for (int j = 0; j < 4; ++j) {
    int tt = t - 3 + j;
    if (tt >= 0) acc += bf2f(P[(size_t)(row - 3 + j) * PJ_N + colofs + cg]) * cw[j];
  }
  float y = acc / (1.f + expf(-acc));
  dst[(size_t)row * 3072 + cg] = f2bf(y);
}

// ---------------------------------------------------------------------------
// Per-(b,h,chunk) precompute of WY operands. grid (32, 6, 2), block 256.
// Qg/Mm store only odd interleaved rows (32 per chunk).
// R18: KdT/Qg/TBV written in scan's FRAGMENT ORDER (see header).
#define KBLD 264
#define R2LD 72
#define WTLD 72
__global__ __launch_bounds__(256) void precompute_chunk(
    const short* __restrict__ Qc, const short* __restrict__ K0c, const short* __restrict__ K1c,
    const short* __restrict__ V0c, const short* __restrict__ V1c,
    const float* __restrict__ Beta0, const float* __restrict__ Beta1, const float* __restrict__ G,
    short* __restrict__ NTW, short* __restrict__ Qg, short* __restrict__ KdT,
    short* __restrict__ Mm, short* __restrict__ TBV, float* __restrict__ dC)
{
  __shared__ short r0[256 * 72];   // kb (64 x KBLD) -> wt (256 x WTLD) -> BVT
  __shared__ float Xs[64 * 64];    // A matrix (f32), consumed by substitution
  __shared__ short r2[64 * 72];    // KK^T (bf16) -> X (bf16)
  const int tid = threadIdx.x;
  const int lane = tid & 63, wv = tid >> 6;
  const int quad = lane >> 4, l16 = lane & 15;
  const int c = blockIdx.x, h = blockIdx.y, b = blockIdx.z;
  const int i0 = c * 32;
  const size_t idx = (size_t)((b * 6 + h) * 32 + c);
  short* kb = r0;
  f32x4 zz = {0.f, 0.f, 0.f, 0.f};
  bf16x8 z8 = {0, 0, 0, 0, 0, 0, 0, 0};

  // per-lane g/beta for interleaved position t = lane; wave-prefix cumsum
  float gv, betaL;
  {
    int t = lane, par = t & 1, i = i0 + (t >> 1);
    size_t gofs = (size_t)(b * 1024 + i) * 6 + h;
    gv = par ? 0.f : G[gofs];
    betaL = par ? Beta1[gofs] : Beta0[gofs];
  }
  float cum = gv;
  #pragma unroll
  for (int off = 1; off < 64; off <<= 1) {
    float nb = __shfl_up(cum, off);
    if (lane >= off) cum += nb;
  }
  float c63 = __shfl(cum, 63);
  float eBt = expf(cum);          // exp(B_t)
  float eRem = expf(c63 - cum);   // exp(B63 - B_t)
  float wsc = betaL * eBt;        // beta_t exp(B_t)
  if (tid == 0) dC[idx] = expf(c63);

  // stage k chunk (interleaved parities) into kb
  {
    int row = tid >> 2, seg = (tid & 3) * 64;
    int par = row & 1, i = i0 + (row >> 1);
    const short* src = (par ? K1c : K0c) + ((size_t)(b * 1024 + i) * 6 + h) * 256 + seg;
    short* dp = kb + row * KBLD + seg;
    #pragma unroll
    for (int e = 0; e < 64; e += 8)
      *(uint4*)(dp + e) = *(const uint4*)(src + e);
  }
  __syncthreads();

  // KK^T (bf16 into r2). wave = t row-tile.
  {
    f32x4 acc[4];
    #pragma unroll
    for (int ts = 0; ts < 4; ++ts) acc[ts] = zz;
    #pragma unroll
    for (int ks = 0; ks < 8; ++ks) {
      bf16x8 af = *(const bf16x8*)(kb + (wv * 16 + l16) * KBLD + ks * 32 + quad * 8);
      #pragma unroll
      for (int ts = 0; ts < 4; ++ts) {
        bf16x8 bfv = *(const bf16x8*)(kb + (ts * 16 + l16) * KBLD + ks * 32 + quad * 8);
        acc[ts] = MFMA(af, bfv, acc[ts]);
      }
    }
    #pragma unroll
    for (int ts = 0; ts < 4; ++ts)
      #pragma unroll
      for (int r = 0; r < 4; ++r)
        r2[(wv * 16 + quad * 4 + r) * R2LD + ts * 16 + l16] = f2bf(acc[ts][r]);
  }
  // QK^T -> M (masked, decayed; odd rows only) directly to global
  {
    f32x4 acc[4];
    #pragma unroll
    for (int ts = 0; ts < 4; ++ts) acc[ts] = zz;
    int t_row = wv * 16 + l16;
    int podd = t_row & 1, iq = i0 + (t_row >> 1);
    const short* qrow = Qc + ((size_t)(b * 1024 + iq) * 6 + h) * 256;
    #pragma unroll
    for (int ks = 0; ks < 8; ++ks) {
      bf16x8 af = z8;
      if (podd) af = *(const bf16x8*)(qrow + ks * 32 + quad * 8);
      #pragma unroll
      for (int ts = 0; ts < 4; ++ts) {
        bf16x8 bfv = *(const bf16x8*)(kb + (ts * 16 + l16) * KBLD + ks * 32 + quad * 8);
        acc[ts] = MFMA(af, bfv, acc[ts]);
      }
    }
    short* Mp = Mm + idx * 2048;
    #pragma unroll
    for (int ts = 0; ts < 4; ++ts)
      #pragma unroll
      for (int r = 1; r < 4; r += 2) {       // odd rows only
        int t = wv * 16 + quad * 4 + r, s = ts * 16 + l16;
        float ct = __shfl(cum, t), cs = __shfl(cum, s);
        float v = (s <= t) ? acc[ts][r] * expf(ct - cs) : 0.f;
        Mp[(t >> 1) * 64 + s] = f2bf(v);
      }
  }
  // Qg (odd rows only), FRAGMENT layout: ((w2*8+ks)*64 + qd*16 + l16q)*8
  // content = exp(B_{2th+1}) q_{2th+1}[ks*32+qd*8..], th = w2*16+l16q.
  {
    int w2 = tid >> 7, ksq = (tid >> 4) & 7, l16q = tid & 15;
    int th = w2 * 16 + l16q;
    int t = th * 2 + 1;
    float sc = __shfl(eBt, t);
    const short* qrow = Qc + ((size_t)(b * 1024 + i0 + th) * 6 + h) * 256;
    short* qgp = Qg + idx * 8192;
    #pragma unroll
    for (int qd = 0; qd < 4; ++qd) {
      bf16x8 v = *(const bf16x8*)(qrow + ksq * 32 + qd * 8);
      bf16x8 w8;
      #pragma unroll
      for (int q2 = 0; q2 < 8; ++q2) w8[q2] = f2bf(bf2f(v[q2]) * sc);
      *(bf16x8*)(qgp + ((size_t)((w2 * 8 + ksq) * 64 + qd * 16 + l16q)) * 8) = w8;
    }
  }
  // KdT: buf[t] = exp(B63-B_t) k_t[d]; FRAGMENT layout:
  // ((dblk*2+ks)*64 + qd*16 + l16k)*8, dblk = d>>4.
  {
    int d = tid;
    short buf[64];
    #pragma unroll
    for (int t = 0; t < 64; ++t) {
      float sc = __shfl(eRem, t);
      buf[t] = f2bf(bf2f(kb[t * KBLD + d]) * sc);
    }
    int dblk = d >> 4, l16k = d & 15;
    short* kp = KdT + idx * 16384;
    #pragma unroll
    for (int ks = 0; ks < 2; ++ks)
      #pragma unroll
      for (int qd = 0; qd < 4; ++qd) {
        uint4 v; __builtin_memcpy(&v, buf + ks * 32 + qd * 8, 16);
        *(uint4*)(kp + ((size_t)((dblk * 2 + ks) * 64 + qd * 16 + l16k)) * 8) = v;
      }
  }
  __syncthreads();

  // C1: cache kb column d = tid in registers
  short colv[64];
  {
    int d = tid;
    #pragma unroll
    for (int t = 0; t < 64; ++t) colv[t] = kb[t * KBLD + d];
  }
  // A precompute (parallel, all 256 threads)
  #pragma unroll
  for (int k = 0; k < 16; ++k) {
    int t = wv + k * 4;
    float bt = __shfl(betaL, t);
    float ct = __shfl(cum, t);
    float a = (lane < t) ? bt * expf(ct - cum) * bf2f(r2[t * R2LD + lane]) : 0.f;
    Xs[t * 64 + lane] = a;
  }
  __syncthreads();
  // C2: wt[d][s] = beta_s exp(B_s) k_s[d] (over r0)
  {
    int d = tid;
    short wrow[64];
    #pragma unroll
    for (int s = 0; s < 64; ++s) wrow[s] = f2bf(bf2f(colv[s]) * __shfl(wsc, s));
    short* wp = r0 + d * WTLD;
    #pragma unroll
    for (int e = 0; e < 64; e += 8) {
      uint4 v; __builtin_memcpy(&v, wrow + e, 16);
      *(uint4*)(wp + e) = v;
    }
  }
  // C3: wave0 solves X = (I+A)^-1, register-resident (R9)
  if (wv == 0) {
    const int j = lane;
    float xcol[64];
    #pragma unroll
    for (int t = 0; t < 64; ++t) {
      float sa0 = 0.f, sa1 = 0.f;
      const float2* ap = (const float2*)(Xs + t * 64);
      #pragma unroll
      for (int s = 0; s + 1 < t; s += 2) {
        float2 av = ap[s >> 1];
        sa0 += av.x * xcol[s];
        sa1 += av.y * xcol[s + 1];
      }
      if (t & 1) sa0 += Xs[t * 64 + (t - 1)] * xcol[t - 1];
      float xv = ((t == j) ? 1.f : 0.f) - (sa0 + sa1);
      xcol[t] = xv;
      r2[t * R2LD + j] = f2bf(xv);
    }
  }
  __syncthreads();
  // NTW = -(X @ W)
  {
    f32x4 acc[4][4];
    #pragma unroll
    for (int i = 0; i < 4; ++i)
      #pragma unroll
      for (int j = 0; j < 4; ++j) acc[i][j] = zz;
    #pragma unroll
    for (int ks = 0; ks < 2; ++ks) {
      bf16x8 af[4], bfv[4];
      #pragma unroll
      for (int tt = 0; tt < 4; ++tt)
        af[tt] = *(const bf16x8*)(r2 + (tt * 16 + l16) * R2LD + ks * 32 + quad * 8);
      #pragma unroll
      for (int dt = 0; dt < 4; ++dt)
        bfv[dt] = *(const bf16x8*)(r0 + ((wv * 4 + dt) * 16 + l16) * WTLD + ks * 32 + quad * 8);
      #pragma unroll
      for (int tt = 0; tt < 4; ++tt)
        #pragma unroll
        for (int dt = 0; dt < 4; ++dt)
          acc[tt][dt] = MFMA(af[tt], bfv[dt], acc[tt][dt]);
    }
    short* np = NTW + idx * 16384;
    #pragma unroll
    for (int tt = 0; tt < 4; ++tt)
      #pragma unroll
      for (int dt = 0; dt < 4; ++dt)
        #pragma unroll
        for (int r = 0; r < 4; ++r) {
          int t = tt * 16 + quad * 4 + r, d = (wv * 4 + dt) * 16 + l16;
          np[t * 256 + d] = f2bf(-acc[tt][dt][r]);
        }
  }
  __syncthreads();
  // TBV = X @ (beta*v), two DV halves through r0; FRAGMENT layout:
  // ((S*4 + tt)*64 + quad*16 + l16)*4, S = vh*16 + wv*4 + vt (slice).
  for (int vh = 0; vh < 2; ++vh) {
    {
      int vl = tid;
      short bv[64];
      #pragma unroll
      for (int t = 0; t < 64; ++t) {
        int par = t & 1, i = i0 + (t >> 1);
        const short* src = (par ? V1c : V0c) + (size_t)(b * 1024 + i) * 3072 + h * 512 + vh * 256 + vl;
        bv[t] = f2bf(bf2f(*src) * __shfl(betaL, t));
      }
      short* bp = r0 + vl * WTLD;
      #pragma unroll
      for (int e = 0; e < 64; e += 8) {
        uint4 v; __builtin_memcpy(&v, bv + e, 16);
        *(uint4*)(bp + e) = v;
      }
    }
    __syncthreads();
    {
      f32x4 acc[4][4];
      #pragma unroll
      for (int i = 0; i < 4; ++i)
        #pragma unroll
        for (int j = 0; j < 4; ++j) acc[i][j] = zz;
      #pragma unroll
      for (int ks = 0; ks < 2; ++ks) {
        bf16x8 af[4], bfv[4];
        #pragma unroll
        for (int tt = 0; tt < 4; ++tt)
          af[tt] = *(const bf16x8*)(r2 + (tt * 16 + l16) * R2LD + ks * 32 + quad * 8);
        #pragma unroll
        for (int vt = 0; vt < 4; ++vt)
          bfv[vt] = *(const bf16x8*)(r0 + ((wv * 4 + vt) * 16 + l16) * WTLD + ks * 32 + quad * 8);
        #pragma unroll
        for (int tt = 0; tt < 4; ++tt)
          #pragma unroll
          for (int vt = 0; vt < 4; ++vt)
            acc[tt][vt] = MFMA(af[tt], bfv[vt], acc[tt][vt]);
      }
      short* tp = TBV + idx * 32768;
      #pragma unroll
      for (int tt = 0; tt < 4; ++tt)
        #pragma unroll
        for (int vt = 0; vt < 4; ++vt) {
          int S = vh * 16 + wv * 4 + vt;
          short w[4];
          #pragma unroll
          for (int r = 0; r < 4; ++r) w[r] = f2bf(acc[tt][vt][r]);
          uint2 uv; __builtin_memcpy(&uv, w, 8);
          *(uint2*)(tp + ((size_t)((S * 4 + tt) * 64 + quad * 16 + l16)) * 4) = uv;
        }
    }
    __syncthreads();
  }
}

// ---------------------------------------------------------------------------
// Scan: 2-wave blocks (128 thr) per (b,h,16-col DV slice). grid 384.
// R16 pipeline + R18 fragment-order coalesced operand loads (lane*16B).
#define SLD 264
#define ULD 72
__global__ __launch_bounds__(128) void scan_kernel(
    const short* __restrict__ NTW, const short* __restrict__ Qg,
    const short* __restrict__ KdT, const short* __restrict__ Mm,
    const short* __restrict__ TBV, const float* __restrict__ dC,
    short* __restrict__ O)
{
  __shared__ short NTWs[2][64 * 256]; // 64KB dbuf, LDS[t][s]=G[t][s^(t&7)]
  __shared__ short S[16 * SLD];       // state slice [v_local][d], bf16
  __shared__ short U[16 * ULD];       // u slice [v_local][t], bf16
  const int tid = threadIdx.x;
  const int lane = tid & 63, w = tid >> 6;
  const int quad = lane >> 4, l16 = lane & 15;
  const int xk = l16 & 7;           // read-side xor key
  const int r2l = lane >> 5;        // staging: row within pair
  const int s32 = lane & 31;        // staging: 16B seg 0..31
  // XCD-aware swizzle (bijective, 384 = 8 xcd * 48)
  const int gid = (blockIdx.x & 7) * 48 + (blockIdx.x >> 3);
  const int bh = gid >> 5, slice = gid & 31;
  const int b = bh / 6, h = bh % 6;
  const int vbase = slice * 16;
  f32x4 zz = {0.f, 0.f, 0.f, 0.f};
  for (int e = tid; e < 16 * SLD; e += 128) S[e] = 0;

  // prologue: stage chunk 0 NTW (own rows) into buf0, full drain
  {
    const short* ntw0 = NTW + (size_t)(bh * 32) * 16384;
    #pragma unroll
    for (int j = 0; j < 16; ++j) {
      int row = 32 * w + 2 * j + r2l;
      gl_lds16(ntw0 + (size_t)row * 256 + ((s32 ^ (row & 7)) << 3),
               &NTWs[0][(32 * w + 2 * j) * 256]);
    }
  }
  __syncthreads();   // drains vmcnt+lgkm: staging-0 + S init visible

  for (int c = 0; c < 32; ++c) {
    size_t idx = (size_t)(bh * 32 + c);
    const short* qg  = Qg  + idx * 8192;
    const short* kdt = KdT + idx * 16384;
    const short* mp  = Mm  + idx * 2048;
    const short* tb  = TBV + idx * 32768;
    short* bufC = &NTWs[c & 1][0];
    short* bufN = &NTWs[(c & 1) ^ 1][0];
    const int cn = (c + 1) & 31;   // wrap: uniform counts, never consumed stale
    const short* ntwN = NTW + (size_t)(bh * 32 + cn) * 16384;

    // top wait: staging for THIS chunk landed (<=4 older O-stores remain)
    asm volatile("s_waitcnt vmcnt(4)" ::: "memory");
    __builtin_amdgcn_sched_barrier(0);

    // reg loads for c (R18: all coalesced, base + lane*16B)
    float dc = dC[idx];
    bf16x8 qgr[8];
    #pragma unroll
    for (int ks = 0; ks < 8; ++ks)
      qgr[ks] = *(const bf16x8*)(qg + ((size_t)((w * 8 + ks) * 64 + lane)) * 8);
    bf16x8 mmr2[2];
    #pragma unroll
    for (int ks = 0; ks < 2; ++ks)
      mmr2[ks] = *(const bf16x8*)(mp + (w * 16 + l16) * 64 + ks * 32 + quad * 8);
    bf16x4 tbv2[2];
    #pragma unroll
    for (int j = 0; j < 2; ++j)
      tbv2[j] = *(const bf16x4*)(tb + ((size_t)((slice * 4 + 2 * w + j) * 64 + lane)) * 4);
    bf16x8 kdr2[2][2][4];
    #pragma unroll
    for (int j = 0; j < 2; ++j)
      #pragma unroll
      for (int ks = 0; ks < 2; ++ks)
        #pragma unroll
        for (int dt = 0; dt < 4; ++dt)
          kdr2[j][ks][dt] = *(const bf16x8*)(
              kdt + ((size_t)((((2 * w + j) * 4 + dt) * 2 + ks) * 64 + lane)) * 8);
    __builtin_amdgcn_sched_barrier(0);

    // issue staging for NEXT chunk into bufN (own rows, 16 gl_lds)
    #pragma unroll
    for (int j = 0; j < 16; ++j) {
      int row = 32 * w + 2 * j + r2l;
      gl_lds16(ntwN + (size_t)row * 256 + ((s32 ^ (row & 7)) << 3),
               bufN + (32 * w + 2 * j) * 256);
    }
    __builtin_amdgcn_sched_barrier(0);

    // --- phase 1: uac = NTW@S0 (own 2 tiles), 2-way chain split ---
    f32x4 uA0 = zz, uB0 = zz, uA1 = zz, uB1 = zz;
    __builtin_amdgcn_s_setprio(1);
    #pragma unroll
    for (int ks = 0; ks < 4; ++ks) {
      bf16x8 bfv0 = *(const bf16x8*)(S + l16 * SLD + ks * 32 + quad * 8);
      bf16x8 bfv1 = *(const bf16x8*)(S + l16 * SLD + (ks + 4) * 32 + quad * 8);
      int gx0 = ks * 4 + quad, gx1 = (ks + 4) * 4 + quad;
      bf16x8 a00 = *(const bf16x8*)(bufC + ((2 * w + 0) * 16 + l16) * 256 + ((gx0 ^ xk) << 3));
      bf16x8 a01 = *(const bf16x8*)(bufC + ((2 * w + 0) * 16 + l16) * 256 + ((gx1 ^ xk) << 3));
      bf16x8 a10 = *(const bf16x8*)(bufC + ((2 * w + 1) * 16 + l16) * 256 + ((gx0 ^ xk) << 3));
      bf16x8 a11 = *(const bf16x8*)(bufC + ((2 * w + 1) * 16 + l16) * 256 + ((gx1 ^ xk) << 3));
      uA0 = MFMA(a00, bfv0, uA0);
      uB0 = MFMA(a01, bfv1, uB0);
      uA1 = MFMA(a10, bfv0, uA1);
      uB1 = MFMA(a11, bfv1, uB1);
    }
    __builtin_amdgcn_s_setprio(0);
    f32x4 uac2[2];
    #pragma unroll
    for (int r = 0; r < 4; ++r) { uac2[0][r] = uA0[r] + uB0[r]; uac2[1][r] = uA1[r] + uB1[r]; }

    // dc/Qg/Mm/TBV done (KdT 16 + staging 16 may remain in flight)
    asm volatile("s_waitcnt vmcnt(32)" ::: "memory");
    __builtin_amdgcn_sched_barrier(0);

    // --- u = uac + TBV -> U (own tiles, b64 writes) ---
    #pragma unroll
    for (int j = 0; j < 2; ++j) {
      short wb[4];
      #pragma unroll
      for (int r = 0; r < 4; ++r) wb[r] = f2bf(uac2[j][r] + bf2f(tbv2[j][r]));
      uint2 uv; __builtin_memcpy(&uv, wb, 8);
      *(uint2*)(U + l16 * ULD + (2 * w + j) * 16 + quad * 4) = uv;
    }
    // bar1: U complete, phase1 S reads retired
    asm volatile("s_waitcnt lgkmcnt(0)" ::: "memory");
    __builtin_amdgcn_s_barrier();
    __builtin_amdgcn_sched_barrier(0);

    // --- oac = Qg @ S0 + M @ u (own tile), 2-way chain split ---
    f32x4 oA = zz, oB = zz;
    #pragma unroll
    for (int ks = 0; ks < 4; ++ks) {
      bf16x8 bfv0 = *(const bf16x8*)(S + l16 * SLD + ks * 32 + quad * 8);
      bf16x8 bfv1 = *(const bf16x8*)(S + l16 * SLD + (ks + 4) * 32 + quad * 8);
      oA = MFMA(qgr[ks], bfv0, oA);
      oB = MFMA(qgr[ks + 4], bfv1, oB);
    }
    {
      bf16x8 ub0 = *(const bf16x8*)(U + l16 * ULD + 0 * 32 + quad * 8);
      bf16x8 ub1 = *(const bf16x8*)(U + l16 * ULD + 1 * 32 + quad * 8);
      oA = MFMA(mmr2[0], ub0, oA);
      oB = MFMA(mmr2[1], ub1, oB);
    }
    f32x4 oac;
    #pragma unroll
    for (int r = 0; r < 4; ++r) oac[r] = oA[r] + oB[r];

    // --- O store (4 stores; may stay in flight across chunk boundary) ---
    #pragma unroll
    for (int r = 0; r < 4; ++r) {
      int th = w * 16 + quad * 4 + r;
      int i = c * 32 + th;
      O[((size_t)(b * 1024 + i) * 6 + h) * 512 + vbase + l16] = f2bf(oac[r]);
    }

    // KdT done (staging 16 + stores 4 may remain)
    asm volatile("s_waitcnt vmcnt(20)" ::: "memory");
    __builtin_amdgcn_sched_barrier(0);

    // bar2: both waves' oac S0-reads retired before S-phase overwrites S
    asm volatile("s_waitcnt lgkmcnt(0)" ::: "memory");
    __builtin_amdgcn_s_barrier();
    __builtin_amdgcn_sched_barrier(0);

    // --- S1 = dc * S0 + KdT @ u (own g2 halves, b64 S reads/writes) ---
    __builtin_amdgcn_s_setprio(1);
    #pragma unroll
    for (int j = 0; j < 2; ++j) {
      const int g2 = 2 * w + j;
      f32x4 sac[4];
      #pragma unroll
      for (int dt = 0; dt < 4; ++dt) {
        bf16x4 sv = *(const bf16x4*)(S + l16 * SLD + (g2 * 4 + dt) * 16 + quad * 4);
        #pragma unroll
        for (int r = 0; r < 4; ++r) sac[dt][r] = dc * bf2f(sv[r]);
      }
      #pragma unroll
      for (int ks = 0; ks < 2; ++ks) {
        bf16x8 bfv = *(const bf16x8*)(U + l16 * ULD + ks * 32 + quad * 8);
        #pragma unroll
        for (int dt = 0; dt < 4; ++dt)
          sac[dt] = MFMA(kdr2[j][ks][dt], bfv, sac[dt]);
      }
      #pragma unroll
      for (int dt = 0; dt < 4; ++dt) {
        short wb[4];
        #pragma unroll
        for (int r = 0; r < 4; ++r) wb[r] = f2bf(sac[dt][r]);
        uint2 uv; __builtin_memcpy(&uv, wb, 8);
        *(uint2*)(S + l16 * SLD + (g2 * 4 + dt) * 16 + quad * 4) = uv;
      }
    }
    __builtin_amdgcn_s_setprio(0);
    // bar3: S complete for next chunk's phase1/oac
    asm volatile("s_waitcnt lgkmcnt(0)" ::: "memory");
    __builtin_amdgcn_s_barrier();
    __builtin_amdgcn_sched_barrier(0);
  }
}

// ---------------------------------------------------------------------------
// RMS-norm over DV per (b,t,h), times silu(gate). grid (2048, 6).
__global__ __launch_bounds__(256) void rms_gate(
    const short* __restrict__ O, const short* __restrict__ P,
    const float* __restrict__ onw, short* __restrict__ OutPre)
{
  __shared__ float red[256];
  int tid = threadIdx.x, h = blockIdx.y, row = blockIdx.x;
  size_t base = ((size_t)row * 6 + h) * 512;
  float a = bf2f(O[base + tid]), b2 = bf2f(O[base + 256 + tid]);
  red[tid] = a * a + b2 * b2;
  __syncthreads();
  for (int s = 128; s > 0; s >>= 1) {
    if (tid < s) red[tid] += red[tid + s];
    __syncthreads();
  }
  float r = rsqrtf(red[0] * (1.f / 512.f) + 1e-5f);
  #pragma unroll
  for (int half = 0; half < 2; ++half) {
    int col = tid + half * 256;
    float ov = half ? b2 : a;
    float g = bf2f(P[(size_t)row * PJ_N + 10752 + h * 512 + col]);
    float sg = g / (1.f + expf(-g));
    OutPre[(size_t)row * 3072 + h * 512 + col] = f2bf(ov * r * onw[col] * sg);
  }
}

// ---------------------------------------------------------------------------
extern "C" void kernel_launch(void* const* d_in, const int* in_sizes, int n_in,
                              void* d_out, int out_size, void* d_ws, size_t ws_size,
                              hipStream_t stream) {
  const float* x        = (const float*)d_in[0];
  const float* q_w      = (const float*)d_in[1];
  const float* k_ws     = (const float*)d_in[2];
  const float* v_ws     = (const float*)d_in[3];
  const float* b_ws     = (const float*)d_in[4];
  const float* a_w      = (const float*)d_in[5];
  const float* g_w      = (const float*)d_in[6];
  const float* o_w      = (const float*)d_in[7];
  const float* q_conv_w = (const float*)d_in[8];
  const float* k_conv   = (const float*)d_in[9];
  const float* v_conv   = (const float*)d_in[10];
  const float* A_log    = (const float*)d_in[11];
  const float* dt_bias  = (const float*)d_in[12];
  const float* o_norm_w = (const float*)d_in[13];
  float* out = (float*)d_out;

  char* ws = (char*)d_ws;
  size_t off = 0;
  auto take = [&](size_t bytes) {
    size_t r = off;
    off += (bytes + 255) & ~(size_t)255;
    return r;
  };
  // Persistent buffers
  short* P  = (short*)(ws + take((size_t)NTOK * PJ_N * 2));   // live 3-8
  short* oT = (short*)(ws + take((size_t)2048 * 3072 * 2));   // live 2-9
  // xbf (step 3 only) reused for Mm (steps 6-7)
  size_t regX = take((size_t)NTOK * 2048 * 2);                // 8.39 MB
  short* xbf = (short*)(ws + regX);
  short* Mm  = (short*)(ws + regX);                           // 1.57 MB
  // Region A: WTall (steps 2-3) reused for NTW|Qg|KdT|TBV (steps 6-7)
  size_t regA = take((size_t)PJ_N * 2048 * 2);                // 56,623,104 B
  short* WTall = (short*)(ws + regA);
  short* NTW = (short*)(ws + regA);
  short* Qg  = NTW + (size_t)384 * 16384;
  short* KdT = Qg  + (size_t)384 * 8192;
  short* TBV = KdT + (size_t)384 * 16384;   // ends exactly at regA + 56,623,104
  // Region B: conv outputs (steps 5-6) reused for O/OutPre (steps 7-9)
  size_t regB = take((size_t)44040192);                       // 44.0 MB
  short* Qc  = (short*)(ws + regB);
  short* K0c = Qc  + (size_t)NTOK * 1536;
  short* K1c = K0c + (size_t)NTOK * 1536;
  short* V0c = K1c + (size_t)NTOK * 1536;
  short* V1c = V0c + (size_t)NTOK * 3072;
  short* O      = (short*)(ws + regB);                        // 12.6 MB
  short* OutPre = O + (size_t)NTOK * 6 * 512;                 // 12.6 MB
  float* Beta0 = (float*)(ws + take((size_t)NTOK * 6 * 4));
  float* Beta1 = (float*)(ws + take((size_t)NTOK * 6 * 4));
  float* G     = (float*)(ws + take((size_t)NTOK * 6 * 4));
  float* dCp   = (float*)(ws + take((size_t)384 * 4));
  if (off > ws_size) return;  // ws too small: no-op (diagnosable, capture-safe)

  // 1) convert x to bf16
  cvt_bf16<<<dim3(NTOK * 2048 / 8 / 256), 256, 0, stream>>>(x, xbf, NTOK * 2048);

  // 2) weight transposes (fp32 -> bf16), LDS-tiled. grid (N/64, K/64).
  transpose_w<<<dim3(24, 32), 256, 0, stream>>>(q_w, WTall, 2048, 1536);
  transpose_w<<<dim3(24, 32), 256, 0, stream>>>(k_ws, WTall + (size_t)1536 * 2048, 2048, 1536);
  transpose_w<<<dim3(24, 32), 256, 0, stream>>>(k_ws + (size_t)2048 * 1536, WTall + (size_t)3072 * 2048, 2048, 1536);
  transpose_w<<<dim3(48, 32), 256, 0, stream>>>(v_ws, WTall + (size_t)4608 * 2048, 2048, 3072);
  transpose_w<<<dim3(48, 32), 256, 0, stream>>>(v_ws + (size_t)2048 * 3072, WTall + (size_t)7680 * 2048, 2048, 3072);
  transpose_w<<<dim3(48, 32), 256, 0, stream>>>(g_w, WTall + (size_t)10752 * 2048, 2048, 3072);
  transpose_w<<<dim3(32, 48), 256, 0, stream>>>(o_w, oT, 3072, 2048);

  // 3) fused projection GEMM (XCD-aware 1-D grid, N padded 108->112 tiles)
  gemm_bt<false><<<dim3(16 * 112), 256, 0, stream>>>(
      xbf, WTall, P, NTOK, PJ_N, 2048);

  // 4) beta / g (fp32 inputs straight from d_in)
  proj_small<<<dim3(NTOK), 64, 0, stream>>>(x, b_ws, a_w, A_log, dt_bias, Beta0, Beta1, G);

  // 5) conv + silu (+ l2norm for q/k)
  conv_norm_qk<<<dim3(NTOK, 6), 256, 0, stream>>>(P, q_conv_w, Qc, 0, 0.0625f);
  conv_norm_qk<<<dim3(NTOK, 6), 256, 0, stream>>>(P, k_conv, K0c, 1536, 1.f);
  conv_norm_qk<<<dim3(NTOK, 6), 256, 0, stream>>>(P, k_conv + (size_t)1536 * 4, K1c, 3072, 1.f);
  conv_v<<<dim3(NTOK, 12), 256, 0, stream>>>(P, v_conv, V0c, 4608);
  conv_v<<<dim3(NTOK, 12), 256, 0, stream>>>(P, v_conv + (size_t)3072 * 4, V1c, 7680);

  // 6) chunk operand precompute (WY form, fragment-order outputs)
  precompute_chunk<<<dim3(32, 6, 2), 256, 0, stream>>>(Qc, K0c, K1c, V0c, V1c,
      Beta0, Beta1, G, NTW, Qg, KdT, Mm, TBV, dCp);

  // 7) sequential chunk scan (384 blocks x 2 waves, coalesced operands)
  scan_kernel<<<dim3(384), 128, 0, stream>>>(NTW, Qg, KdT, Mm, TBV, dCp, O);

  // 8) rms-norm * silu(gate)
  rms_gate<<<dim3(NTOK, 6), 256, 0, stream>>>(O, P, o_norm_w, OutPre);

  // 9) output projection (fp32 out)
  gemm_bt<true><<<dim3(16 * 16), 256, 0, stream>>>(
      OutPre, oT, out, NTOK, 2048, 3072);
}